// Round 17
// baseline (94.229 us; speedup 1.0000x reference)
//
#include <hip/hip_runtime.h>
#include <stdint.h>

typedef unsigned long long u64;
typedef unsigned int u32;

#define N_ANCH     36864
#define PRE_NMS_N  6000
#define POST_NMS_N 300
#define NBINS_F    8192     // fallback full bin count
#define NBINS_H    2048     // happy-path bins == prefilter width
#define PF_BIN     2048     // append keys with bin < 2048 (score >= 0.75): E=8018 >> 6000
#define SEG_CAP    448      // per-block segment cap (E=223, ~15 sigma)
#define GKH_CAP    8192
#define NWORDS     94       // ceil(6000/64)
#define S_WORDS    8        // eager words (candidates 0..511)
#define S_ROWS     512
#define GRID_A     36       // 36 x 1024 == N_ANCH
#define GRID_B     256      // rows {b, b+256} per block

// ---- workspace layout (bytes) ----
#define OFF_BBOX   0            // float4 bbox[36864]       589824
#define OFF_KEYS   589824       // u64 keys[36864]          294912 (fallback only)
#define OFF_SBOX   884736       // float4 sboxes[6000]       96000
#define OFF_IREM   980736       // u64 irem[94]                752
#define OFF_CTR    981488       // ctrA u64, ctrB u64, bcnt u32[36] (160 B)
#define OFF_GKRAW  981648       // u64 gkraw[36*448]        129024
#define OFF_MCOL   1110672      // u64 Mcol[8*512]           32768 (word-major)
#define WS_FULL    (OFF_MCOL + (size_t)S_WORDS * S_ROWS * 8)

// Value-uniform monotone bin: higher score -> lower bin.
__device__ __forceinline__ u32 score_bin(float s) {
    float v = fminf(fmaxf(s, 0.0f), 1.0f);
    u32 q = (u32)(v * 8192.0f);
    if (q > 8191u) q = 8191u;
    return 8191u - q;
}

// key = bin(16) | sortable_score(32) | idx(16); ascending u64 ==
// (score desc, idx asc) exactly (bin monotone in score).
__device__ __forceinline__ u64 make_key(float s, u32 bin, u32 idx) {
    u32 u = __float_as_uint(s);
    u32 sortable = u ^ ((u >> 31) ? 0xFFFFFFFFu : 0x80000000u);
    u32 hi = ~sortable;
    return ((u64)bin << 48) | ((u64)hi << 16) | (u64)idx;
}

__device__ __forceinline__ u64 readlane_u64(u64 v, int l) {
    u32 lo = __builtin_amdgcn_readlane((u32)(v & 0xFFFFFFFFull), l);
    u32 hi = __builtin_amdgcn_readlane((u32)(v >> 32), l);
    return ((u64)hi << 32) | (u64)lo;
}

__device__ __forceinline__ int nth_set_bit(u64 m, int n) {
    int pos = 0;
    u32 c = __popc((u32)m);
    if ((u32)n >= c) { n -= c; pos = 32; m >>= 32; }
    u32 x = (u32)m;
    c = __popc(x & 0xFFFFu);
    if ((u32)n >= c) { n -= c; pos += 16; x >>= 16; }
    c = __popc(x & 0xFFu);
    if ((u32)n >= c) { n -= c; pos += 8; x >>= 8; }
    c = __popc(x & 0xFu);
    if ((u32)n >= c) { n -= c; pos += 4; x >>= 4; }
    c = __popc(x & 0x3u);
    if ((u32)n >= c) { n -= c; pos += 2; x >>= 2; }
    c = x & 1u;
    if ((u32)n >= c) { pos += 1; }
    return pos;
}

// EXACT reference IoU decision (identical expression tree to all prior rounds)
__device__ __forceinline__ bool iou_gt(float4 a, float4 b) {
    float aa = (a.z - a.x) * (a.w - a.y);
    float ab = (b.z - b.x) * (b.w - b.y);
    float xx1 = fmaxf(a.x, b.x), yy1 = fmaxf(a.y, b.y);
    float xx2 = fminf(a.z, b.z), yy2 = fminf(a.w, b.w);
    float inter = fmaxf(xx2 - xx1, 0.0f) * fmaxf(yy2 - yy1, 0.0f);
    float iou = inter / (aa + ab - inter + 1e-9f);
    return iou > 0.7f;
}

// Timing probe: empty kernel to measure per-launch overhead (3x in sequence).
__global__ void k_nop() {}

// ===== K_FRONT: VERBATIM R16. IDEMPOTENT: safe to launch multiple times
//       per call (monotone-modulo arrival triggers exactly once per launch;
//       all outputs rewritten with identical values). =====
__global__ __launch_bounds__(1024) void k_front(const float4* __restrict__ anchors,
                                                const float* __restrict__ cls,
                                                const float4* __restrict__ reg,
                                                const int* __restrict__ img_w,
                                                const int* __restrict__ img_h,
                                                float4* __restrict__ bbox,
                                                u64* __restrict__ keys,
                                                u64* __restrict__ gkraw,
                                                u32* __restrict__ bcnt,
                                                float4* __restrict__ sboxes,
                                                u64* __restrict__ irem,
                                                u64* __restrict__ ctrA) {
    __shared__ u32 histoffs[NBINS_H + 1];  // happy hist -> offsets (8196 B)
    __shared__ u32 cntH[NBINS_H];
    __shared__ u32 wsum[16];
    __shared__ u64 gkB[GKH_CAP];           // 64 KiB
    __shared__ u32 psum[1024];             // fallback scan
    __shared__ u32 histF[NBINS_F];         // fallback (32 KiB)
    __shared__ u32 cntF[NBINS_F];          // fallback (32 KiB)
    __shared__ u64 iremL[NWORDS];
    __shared__ u32 blkCnt, mB, mM, lastflag, offs_top;

    int tid = threadIdx.x, lane = tid & 63, wave = tid >> 6;
    int gi = blockIdx.x * 1024 + tid;      // exact: 36*1024 == N_ANCH

    if (tid == 0) blkCnt = 0u;
    __syncthreads();

    // ---- decode + clip + valid + key (EXACT reference arithmetic) ----
    {
        float4 a = anchors[gi];
        float4 r = reg[gi];
        float w  = a.z - a.x, h = a.w - a.y;
        float cx = a.x + 0.5f * w, cy = a.y + 0.5f * h;
        float pcx = r.x * w + cx, pcy = r.y * h + cy;
        float pw = expf(r.z) * w,  ph = expf(r.w) * h;
        float b0 = pcx - 0.5f * pw, b1 = pcy - 0.5f * ph;
        float b2 = pcx + 0.5f * pw, b3 = pcy + 0.5f * ph;

        float fh = (float)img_h[0], fw = (float)img_w[0];
        // reference: cols 0,2 clipped to [0, img_h]; cols 1,3 to [0, img_w]
        b0 = fminf(fmaxf(b0, 0.0f), fh);
        b2 = fminf(fmaxf(b2, 0.0f), fh);
        b1 = fminf(fmaxf(b1, 0.0f), fw);
        b3 = fminf(fmaxf(b3, 0.0f), fw);

        bool valid = (b2 - b0 >= 16.0f) && (b3 - b1 >= 16.0f);
        float score = valid ? cls[gi] : -1e9f;

        bbox[gi] = make_float4(b0, b1, b2, b3);
        u32 bin = score_bin(score);
        u64 key = make_key(score, bin, (u32)gi);
        keys[gi] = key;

        // wave-aggregated append into this block's PRIVATE segment (coalesced,
        // LDS counter only -- no cross-XCD atomic traffic)
        bool qf = bin < (u32)PF_BIN;
        u64 ball = __ballot(qf);
        u32 n = (u32)__popcll(ball);
        u32 wbase = 0;
        if (lane == 0 && n) wbase = atomicAdd(&blkCnt, n);
        wbase = (u32)__shfl((int)wbase, 0, 64);
        if (qf) {
            u32 pos = wbase + (u32)__popcll(ball & ((1ull << lane) - 1ull));
            if (pos < SEG_CAP) gkraw[(size_t)blockIdx.x * SEG_CAP + pos] = key;
        }
    }

    // ---- arrival (monotone modulo counter: poison-proof, no reset) ----
    __syncthreads();
    if (tid == 0) {
        bcnt[blockIdx.x] = blkCnt;
        __threadfence();
        u64 old = atomicAdd(ctrA, 1ull);
        lastflag = ((old % (u64)GRID_A) == (u64)(GRID_A - 1)) ? 1u : 0u;
    }
    __syncthreads();
    if (!lastflag) return;
    __threadfence();   // acquire: see all blocks' bbox/keys/gkraw/bcnt

    if (tid < NWORDS) iremL[tid] = ~0ull;

    // ---- gather segment counts (uniform loop, scalarizes) ----
    u32 count = 0; bool ovf = false;
    for (int b = 0; b < GRID_A; ++b) {
        u32 c = bcnt[b];
        count += c;
        ovf = ovf || (c > (u32)SEG_CAP);
    }
    bool happy = (count >= (u32)PRE_NMS_N) && !ovf;

    if (happy) {
        // top-6000 subset proof: every non-appended key has bin >= PF_BIN >
        // any appended bin, and count >= 6000 appended keys exist.
        for (int b = tid; b < NBINS_H; b += 1024) { histoffs[b] = 0u; cntH[b] = 0u; }
        __syncthreads();
        for (int i = tid; i < GRID_A * SEG_CAP; i += 1024) {
            int b = i / SEG_CAP, o = i - b * SEG_CAP;
            if (o < (int)bcnt[b])
                atomicAdd(&histoffs[(u32)(gkraw[i] >> 48)], 1u);
        }
        __syncthreads();

        // 2-barrier block scan (shfl wave scan + 16-partial combine)
        u32 l0 = histoffs[2 * tid], l1 = histoffs[2 * tid + 1];
        u32 s = l0 + l1;
        u32 incv = s;
#pragma unroll
        for (int off = 1; off < 64; off <<= 1) {
            u32 v = (u32)__shfl_up((int)incv, off, 64);
            if (lane >= off) incv += v;
        }
        if (lane == 63) wsum[wave] = incv;
        __syncthreads();
        if (tid == 0) {
            u32 run = 0;
#pragma unroll
            for (int k2 = 0; k2 < 16; ++k2) { u32 t2 = wsum[k2]; wsum[k2] = run; run += t2; }
        }
        __syncthreads();
        u32 incl = wsum[wave] + incv;
        u32 excl = incl - s;
        histoffs[2 * tid] = excl;
        histoffs[2 * tid + 1] = excl + l0;
        if (tid == 1023) histoffs[NBINS_H] = incl;
        if (excl < (u32)PRE_NMS_N && incl >= (u32)PRE_NMS_N) {
            if (excl + l0 >= (u32)PRE_NMS_N) { mB = 2 * tid;     mM = excl + l0; }
            else                             { mB = 2 * tid + 1; mM = incl; }
        }
        __syncthreads();

        u32 B = mB;
        for (int i = tid; i < GRID_A * SEG_CAP; i += 1024) {
            int b = i / SEG_CAP, o = i - b * SEG_CAP;
            if (o < (int)bcnt[b]) {
                u64 k = gkraw[i];
                u32 bn = (u32)(k >> 48);
                if (bn <= B) {
                    u32 p = histoffs[bn] + atomicAdd(&cntH[bn], 1u);
                    if (p < (u32)GKH_CAP) gkB[p] = k;
                }
            }
        }
        __syncthreads();
        u32 Mtot = mM > (u32)GKH_CAP ? (u32)GKH_CAP : mM;
        for (int i = tid; i < (int)Mtot; i += 1024) {
            u64 k = gkB[i];
            u32 bn = (u32)(k >> 48);
            u32 st = histoffs[bn], en = histoffs[bn + 1];
            if (en > (u32)GKH_CAP) en = (u32)GKH_CAP;
            u32 rr = st;
            for (u32 t = st; t < en; ++t) rr += (gkB[t] < k) ? 1u : 0u;
            if (rr < (u32)PRE_NMS_N) {
                u32 idx = (u32)(k & 0xFFFFu);
                sboxes[rr] = bbox[idx];   // appended => bin<2048 => score>=0.75 => valid
            }
        }
        // top-6000 provably all valid -> irem is the pad-only constant
        if (tid < 93) iremL[tid] = 0ull;
        if (tid == 93) iremL[93] = 0xFFFF000000000000ull;  // ranks 6000..6015 removed
    } else {
        // ---- exact fallback: full 8192-bin path over all keys (R8-proven) ----
        for (int b = tid; b < NBINS_F; b += 1024) { histF[b] = 0u; cntF[b] = 0u; }
        __syncthreads();
        for (int i = tid; i < N_ANCH; i += 1024)
            atomicAdd(&histF[(u32)(keys[i] >> 48)], 1u);
        __syncthreads();
        u32 loc[8]; u32 s = 0;
        int base8 = tid * 8;
#pragma unroll
        for (int t = 0; t < 8; ++t) { loc[t] = histF[base8 + t]; s += loc[t]; }
        psum[tid] = s;
        __syncthreads();
        for (int off = 1; off < 1024; off <<= 1) {
            u32 v = (tid >= off) ? psum[tid - off] : 0u;
            __syncthreads();
            psum[tid] += v;
            __syncthreads();
        }
        u32 incl = psum[tid], excl = incl - s;
        u32 run = excl;
#pragma unroll
        for (int t = 0; t < 8; ++t) { histF[base8 + t] = run; run += loc[t]; }
        if (tid == 1023) offs_top = incl;
        if (excl < (u32)PRE_NMS_N && incl >= (u32)PRE_NMS_N) {
            u32 c = excl;
#pragma unroll
            for (int t = 0; t < 8; ++t) {
                if (c + loc[t] >= (u32)PRE_NMS_N) { mB = (u32)(base8 + t); mM = c + loc[t]; break; }
                c += loc[t];
            }
        }
        __syncthreads();
        u32 B = mB;
        for (int i = tid; i < N_ANCH; i += 1024) {
            u64 k = keys[i];
            u32 bn = (u32)(k >> 48);
            if (bn <= B) {
                u32 p = histF[bn] + atomicAdd(&cntF[bn], 1u);
                if (p < (u32)GKH_CAP) gkB[p] = k;
            }
        }
        __syncthreads();
        u32 Mtot = mM > (u32)GKH_CAP ? (u32)GKH_CAP : mM;
        for (int i = tid; i < (int)Mtot; i += 1024) {
            u64 k = gkB[i];
            u32 bn = (u32)(k >> 48);
            u32 st = histF[bn];
            u32 en = (bn + 1 < (u32)NBINS_F) ? histF[bn + 1] : offs_top;
            if (en > (u32)GKH_CAP) en = (u32)GKH_CAP;
            u32 rr = st;
            for (u32 t = st; t < en; ++t) rr += (gkB[t] < k) ? 1u : 0u;
            if (rr < (u32)PRE_NMS_N) {
                u32 idx = (u32)(k & 0xFFFFu);
                float4 b = bbox[idx];
                sboxes[rr] = b;
                bool valid = (b.z - b.x >= 16.0f) && (b.w - b.y >= 16.0f);
                if (valid) atomicAnd(&iremL[rr >> 6], ~(1ull << (rr & 63)));
            }
        }
    }
    __syncthreads();
    if (tid < NWORDS) irem[tid] = iremL[tid];
}

// ===== K_BACK: VERBATIM R16 (idempotent for the same reasons). =====
__global__ __launch_bounds__(64) void k_back(const float4* __restrict__ sboxes,
                                             const u64* __restrict__ irem,
                                             u64* __restrict__ Mcol,
                                             u64* __restrict__ ctrB,
                                             float* __restrict__ out) {
    __shared__ float4 sbL[PRE_NMS_N];      // fallback staging only (96000 B)
    __shared__ u64 S[S_WORDS * S_ROWS];    // 32768 B == Mcol layout
    __shared__ u64 kmaskLDS[NWORDS];
    __shared__ u32 kbaseLDS[NWORDS];
    __shared__ u32 lastflag;
    int lane = threadIdx.x;

    // ---- eager: rows {bid, bid+256}, words row>>6 .. 7; write word-major ----
#pragma unroll
    for (int t = 0; t < 2; ++t) {
        int i = blockIdx.x + (t << 8);     // < 512
        float4 bi = sboxes[i];
        for (int w = i >> 6; w < S_WORDS; ++w) {
            int j = (w << 6) + lane;       // < 512
            bool sup = (j > i) && iou_gt(bi, sboxes[j]);
            u64 m = __ballot(sup);
            if (lane == 0) Mcol[w * S_ROWS + i] = m;
        }
    }

    // ---- arrival (monotone modulo counter) ----
    __syncthreads();
    if (lane == 0) {
        __threadfence();
        u64 old = atomicAdd(ctrB, 1ull);
        lastflag = ((old % (u64)GRID_B) == (u64)(GRID_B - 1)) ? 1u : 0u;
    }
    __syncthreads();
    if (!lastflag) return;
    __threadfence();   // acquire

    for (int idx = lane; idx < S_WORDS * S_ROWS; idx += 64)
        S[idx] = Mcol[idx];                // coalesced: S layout == Mcol layout
    __syncthreads();
    u64 lanebit = 1ull << lane;
    u64 riem0 = irem[lane];
    u64 riem1 = (lane < NWORDS - 64) ? irem[64 + lane] : ~0ull;

    int kc = 0, wend = 0;
    bool sbStaged = false;
    for (int w = 0; w < NWORDS && kc < POST_NMS_N; ++w) {
        int q0 = w << 6;
        u64 avail, myrow;

        if (w < S_WORDS) {
            u64 add = 0;
            for (int wp = 0; wp < w; ++wp) {
                u64 km = kmaskLDS[wp];
                if (km & lanebit) add |= S[w * S_ROWS + (wp << 6) + lane];
            }
            if (w) {
#pragma unroll
                for (int off = 32; off >= 1; off >>= 1) add |= __shfl_xor(add, off, 64);
            }
            u64 iw = readlane_u64(riem0, w);
            avail = ~(iw | add);
            u64 diag = S[w * S_ROWS + q0 + lane];
            bool ina = (avail >> lane) & 1ull;
            myrow = ina ? (diag & avail) : 0ull;
        } else {
            // exact on-the-fly fallback (only if >212 of first 512 suppressed)
            if (!sbStaged) {
                for (int r2 = lane; r2 < PRE_NMS_N; r2 += 64) sbL[r2] = sboxes[r2];
                sbStaged = true;
                __syncthreads();
            }
            int j = q0 + lane; if (j >= PRE_NMS_N) j = PRE_NMS_N - 1;
            float4 bj = sbL[j];
            bool sup = false;
            for (int wp = 0; wp < w; ++wp) {
                u64 km = kmaskLDS[wp];
                while (km) {
                    int b = __ffsll((unsigned long long)km) - 1; km &= km - 1;
                    sup = sup || iou_gt(sbL[(wp << 6) + b], bj);
                }
            }
            u64 iw = (w < 64) ? readlane_u64(riem0, w) : readlane_u64(riem1, w - 64);
            avail = ~(iw | __ballot(sup));
            int irow = q0 + lane;
            bool rowok = (irow < PRE_NMS_N) && ((avail >> lane) & 1ull);
            float4 bi2 = sbL[rowok ? irow : 0];
            u64 my = 0;
            for (int m2 = lane + 1; m2 < 64; ++m2) {
                int jj = q0 + m2;
                if (jj >= PRE_NMS_N) break;
                if (iou_gt(bi2, sbL[jj])) my |= (1ull << m2);
            }
            myrow = rowok ? (my & avail) : 0ull;
        }

        u64 src = __ballot(myrow != 0ull);
        u64 tor = myrow;
#pragma unroll
        for (int off = 32; off >= 1; off >>= 1) tor |= __shfl_xor(tor, off, 64);
        u64 active = (src | tor) & avail;

        u64 rm = 0;
        while (active) {
            int b = __ffsll((unsigned long long)active) - 1;
            active &= active - 1;
            if (!((rm >> b) & 1ull)) rm |= readlane_u64(myrow, b);
        }
        u64 keptw = avail & ~rm;

        if (lane == 0) { kmaskLDS[w] = keptw; kbaseLDS[w] = (u32)kc; }
        kc += __popcll(keptw);
        wend = w + 1;
    }

    int nout = kc < POST_NMS_N ? kc : POST_NMS_N;
    for (int r2 = lane; r2 < POST_NMS_N; r2 += 64) {
        float4 v = make_float4(0.0f, 0.0f, 0.0f, 0.0f);
        if (r2 < nout) {
            int w = 0;
            while (w + 1 < wend && (int)kbaseLDS[w + 1] <= r2) ++w;
            int n = r2 - (int)kbaseLDS[w];
            int idx = (w << 6) + nth_set_bit(kmaskLDS[w], n);
            v = sboxes[idx];
        }
        ((float4*)out)[r2] = v;
    }
}

extern "C" void kernel_launch(void* const* d_in, const int* in_sizes, int n_in,
                              void* d_out, int out_size, void* d_ws, size_t ws_size,
                              hipStream_t stream) {
    const float4* anchors = (const float4*)d_in[0];
    const float*  cls     = (const float*)d_in[1];
    const float4* reg     = (const float4*)d_in[2];
    const int*    img_w   = (const int*)d_in[3];
    const int*    img_h   = (const int*)d_in[4];

    char* ws = (char*)d_ws;
    float4* bbox   = (float4*)(ws + OFF_BBOX);
    u64*    keys   = (u64*)   (ws + OFF_KEYS);
    float4* sboxes = (float4*)(ws + OFF_SBOX);
    u64*    irem   = (u64*)   (ws + OFF_IREM);
    u64*    ctrA   = (u64*)   (ws + OFF_CTR);
    u64*    ctrB   = (u64*)   (ws + OFF_CTR + 8);
    u32*    bcnt   = (u32*)   (ws + OFF_CTR + 16);
    u64*    gkraw  = (u64*)   (ws + OFF_GKRAW);
    u64*    Mcol   = (u64*)   (ws + OFF_MCOL);

    // MEASUREMENT ROUND: k_front is idempotent; the extra k_front + 3x k_nop
    // decompose dur into {kf, kb, per-launch gap g}:
    //   N - 61.3 = kf + 3*nop + 4g   (with R15: kf + g ~= 30)
    k_front<<<dim3(GRID_A), dim3(1024), 0, stream>>>(
        anchors, cls, reg, img_w, img_h, bbox, keys, gkraw, bcnt, sboxes, irem, ctrA);

    k_nop<<<dim3(1), dim3(64), 0, stream>>>();
    k_nop<<<dim3(1), dim3(64), 0, stream>>>();
    k_nop<<<dim3(1), dim3(64), 0, stream>>>();

    k_front<<<dim3(GRID_A), dim3(1024), 0, stream>>>(
        anchors, cls, reg, img_w, img_h, bbox, keys, gkraw, bcnt, sboxes, irem, ctrA);

    k_back<<<dim3(GRID_B), dim3(64), 0, stream>>>(
        sboxes, irem, Mcol, ctrB, (float*)d_out);
}

// Round 18
// 59.756 us; speedup vs baseline: 1.5769x; 1.5769x over previous
//
#include <hip/hip_runtime.h>
#include <stdint.h>

typedef unsigned long long u64;
typedef unsigned int u32;

#define N_ANCH     36864
#define PRE_NMS_N  6000
#define POST_NMS_N 300
#define NBINS_F    8192     // fallback full bin count
#define NBINS_H    2048     // happy-path bins == prefilter width
#define PF_BIN     2048     // append keys with bin < 2048 (score >= 0.75): E=8018 >> 6000
#define SEG_CAP    448      // per-block segment cap (E=223, ~15 sigma)
#define GKH_CAP    8192
#define NWORDS     94       // ceil(6000/64)
#define S_WORDS    8        // eager words (candidates 0..511)
#define S_ROWS     512
#define GRID_A     36       // 36 x 1024 == N_ANCH
#define GRID_B     256      // rows {b, b+256} per block

// ---- workspace layout (bytes) ----
#define OFF_BBOX   0            // float4 bbox[36864]       589824
#define OFF_KEYS   589824       // u64 keys[36864]          294912 (fallback only)
#define OFF_SBOX   884736       // float4 sboxes[6000]       96000
#define OFF_IREM   980736       // u64 irem[94]                752
#define OFF_BCNT   981488       // u32 bcnt[36]                144
#define OFF_GKRAW  981648       // u64 gkraw[36*448]        129024
#define OFF_MCOL   1110672      // u64 Mcol[8*512]           32768 (word-major)
#define WS_FULL    (OFF_MCOL + (size_t)S_WORDS * S_ROWS * 8)

// Value-uniform monotone bin: higher score -> lower bin.
__device__ __forceinline__ u32 score_bin(float s) {
    float v = fminf(fmaxf(s, 0.0f), 1.0f);
    u32 q = (u32)(v * 8192.0f);
    if (q > 8191u) q = 8191u;
    return 8191u - q;
}

// key = bin(16) | sortable_score(32) | idx(16); ascending u64 ==
// (score desc, idx asc) exactly (bin monotone in score).
__device__ __forceinline__ u64 make_key(float s, u32 bin, u32 idx) {
    u32 u = __float_as_uint(s);
    u32 sortable = u ^ ((u >> 31) ? 0xFFFFFFFFu : 0x80000000u);
    u32 hi = ~sortable;
    return ((u64)bin << 48) | ((u64)hi << 16) | (u64)idx;
}

__device__ __forceinline__ u64 readlane_u64(u64 v, int l) {
    u32 lo = __builtin_amdgcn_readlane((u32)(v & 0xFFFFFFFFull), l);
    u32 hi = __builtin_amdgcn_readlane((u32)(v >> 32), l);
    return ((u64)hi << 32) | (u64)lo;
}

__device__ __forceinline__ int nth_set_bit(u64 m, int n) {
    int pos = 0;
    u32 c = __popc((u32)m);
    if ((u32)n >= c) { n -= c; pos = 32; m >>= 32; }
    u32 x = (u32)m;
    c = __popc(x & 0xFFFFu);
    if ((u32)n >= c) { n -= c; pos += 16; x >>= 16; }
    c = __popc(x & 0xFFu);
    if ((u32)n >= c) { n -= c; pos += 8; x >>= 8; }
    c = __popc(x & 0xFu);
    if ((u32)n >= c) { n -= c; pos += 4; x >>= 4; }
    c = __popc(x & 0x3u);
    if ((u32)n >= c) { n -= c; pos += 2; x >>= 2; }
    c = x & 1u;
    if ((u32)n >= c) { pos += 1; }
    return pos;
}

// EXACT reference IoU decision (identical expression tree to all prior rounds)
__device__ __forceinline__ bool iou_gt(float4 a, float4 b) {
    float aa = (a.z - a.x) * (a.w - a.y);
    float ab = (b.z - b.x) * (b.w - b.y);
    float xx1 = fmaxf(a.x, b.x), yy1 = fmaxf(a.y, b.y);
    float xx2 = fminf(a.z, b.z), yy2 = fminf(a.w, b.w);
    float inter = fmaxf(xx2 - xx1, 0.0f) * fmaxf(yy2 - yy1, 0.0f);
    float iou = inter / (aa + ab - inter + 1e-9f);
    return iou > 0.7f;
}

// ===== K_DECODE: decode + segmented coalesced append. NO fences, NO
//       global atomics -- kernel boundary provides visibility. =====
__global__ __launch_bounds__(1024) void k_decode(const float4* __restrict__ anchors,
                                                 const float* __restrict__ cls,
                                                 const float4* __restrict__ reg,
                                                 const int* __restrict__ img_w,
                                                 const int* __restrict__ img_h,
                                                 float4* __restrict__ bbox,
                                                 u64* __restrict__ keys,
                                                 u64* __restrict__ gkraw,
                                                 u32* __restrict__ bcnt) {
    __shared__ u32 blkCnt;
    int tid = threadIdx.x, lane = tid & 63;
    int gi = blockIdx.x * 1024 + tid;      // exact: 36*1024 == N_ANCH

    if (tid == 0) blkCnt = 0u;
    __syncthreads();

    float4 a = anchors[gi];
    float4 r = reg[gi];
    float w  = a.z - a.x, h = a.w - a.y;
    float cx = a.x + 0.5f * w, cy = a.y + 0.5f * h;
    float pcx = r.x * w + cx, pcy = r.y * h + cy;
    float pw = expf(r.z) * w,  ph = expf(r.w) * h;
    float b0 = pcx - 0.5f * pw, b1 = pcy - 0.5f * ph;
    float b2 = pcx + 0.5f * pw, b3 = pcy + 0.5f * ph;

    float fh = (float)img_h[0], fw = (float)img_w[0];
    // reference: cols 0,2 clipped to [0, img_h]; cols 1,3 to [0, img_w]
    b0 = fminf(fmaxf(b0, 0.0f), fh);
    b2 = fminf(fmaxf(b2, 0.0f), fh);
    b1 = fminf(fmaxf(b1, 0.0f), fw);
    b3 = fminf(fmaxf(b3, 0.0f), fw);

    bool valid = (b2 - b0 >= 16.0f) && (b3 - b1 >= 16.0f);
    float score = valid ? cls[gi] : -1e9f;

    bbox[gi] = make_float4(b0, b1, b2, b3);
    u32 bin = score_bin(score);
    u64 key = make_key(score, bin, (u32)gi);
    keys[gi] = key;

    // wave-aggregated append into this block's PRIVATE segment (coalesced,
    // LDS counter only -- no cross-XCD atomic traffic)
    bool qf = bin < (u32)PF_BIN;
    u64 ball = __ballot(qf);
    u32 n = (u32)__popcll(ball);
    u32 wbase = 0;
    if (lane == 0 && n) wbase = atomicAdd(&blkCnt, n);
    wbase = (u32)__shfl((int)wbase, 0, 64);
    if (qf) {
        u32 pos = wbase + (u32)__popcll(ball & ((1ull << lane) - 1ull));
        if (pos < SEG_CAP) gkraw[(size_t)blockIdx.x * SEG_CAP + pos] = key;
    }

    __syncthreads();
    if (tid == 0) bcnt[blockIdx.x] = blkCnt;
}

// ===== K_SELECT: single block; R13-proven selection chain -> sboxes + irem. =====
__global__ __launch_bounds__(1024) void k_select(const u64* __restrict__ keys,
                                                 const u64* __restrict__ gkraw,
                                                 const u32* __restrict__ bcnt,
                                                 const float4* __restrict__ bbox,
                                                 float4* __restrict__ sboxes,
                                                 u64* __restrict__ irem) {
    __shared__ u32 histoffs[NBINS_H + 1];  // happy hist -> offsets (8196 B)
    __shared__ u32 cntH[NBINS_H];
    __shared__ u32 wsum[16];
    __shared__ u64 gkB[GKH_CAP];           // 64 KiB
    __shared__ u32 psum[1024];             // fallback scan
    __shared__ u32 histF[NBINS_F];         // fallback (32 KiB)
    __shared__ u32 cntF[NBINS_F];          // fallback (32 KiB)
    __shared__ u64 iremL[NWORDS];
    __shared__ u32 mB, mM, offs_top;

    int tid = threadIdx.x, lane = tid & 63, wave = tid >> 6;

    if (tid < NWORDS) iremL[tid] = ~0ull;

    // ---- gather segment counts (uniform loop, scalarizes) ----
    u32 count = 0; bool ovf = false;
    for (int b = 0; b < GRID_A; ++b) {
        u32 c = bcnt[b];
        count += c;
        ovf = ovf || (c > (u32)SEG_CAP);
    }
    bool happy = (count >= (u32)PRE_NMS_N) && !ovf;

    if (happy) {
        // top-6000 subset proof: every non-appended key has bin >= PF_BIN >
        // any appended bin, and count >= 6000 appended keys exist.
        for (int b = tid; b < NBINS_H; b += 1024) { histoffs[b] = 0u; cntH[b] = 0u; }
        __syncthreads();
        for (int i = tid; i < GRID_A * SEG_CAP; i += 1024) {
            int b = i / SEG_CAP, o = i - b * SEG_CAP;
            if (o < (int)bcnt[b])
                atomicAdd(&histoffs[(u32)(gkraw[i] >> 48)], 1u);
        }
        __syncthreads();

        // 2-barrier block scan (shfl wave scan + 16-partial combine)
        u32 l0 = histoffs[2 * tid], l1 = histoffs[2 * tid + 1];
        u32 s = l0 + l1;
        u32 incv = s;
#pragma unroll
        for (int off = 1; off < 64; off <<= 1) {
            u32 v = (u32)__shfl_up((int)incv, off, 64);
            if (lane >= off) incv += v;
        }
        if (lane == 63) wsum[wave] = incv;
        __syncthreads();
        if (tid == 0) {
            u32 run = 0;
#pragma unroll
            for (int k2 = 0; k2 < 16; ++k2) { u32 t2 = wsum[k2]; wsum[k2] = run; run += t2; }
        }
        __syncthreads();
        u32 incl = wsum[wave] + incv;
        u32 excl = incl - s;
        histoffs[2 * tid] = excl;
        histoffs[2 * tid + 1] = excl + l0;
        if (tid == 1023) histoffs[NBINS_H] = incl;
        if (excl < (u32)PRE_NMS_N && incl >= (u32)PRE_NMS_N) {
            if (excl + l0 >= (u32)PRE_NMS_N) { mB = 2 * tid;     mM = excl + l0; }
            else                             { mB = 2 * tid + 1; mM = incl; }
        }
        __syncthreads();

        u32 B = mB;
        for (int i = tid; i < GRID_A * SEG_CAP; i += 1024) {
            int b = i / SEG_CAP, o = i - b * SEG_CAP;
            if (o < (int)bcnt[b]) {
                u64 k = gkraw[i];
                u32 bn = (u32)(k >> 48);
                if (bn <= B) {
                    u32 p = histoffs[bn] + atomicAdd(&cntH[bn], 1u);
                    if (p < (u32)GKH_CAP) gkB[p] = k;
                }
            }
        }
        __syncthreads();
        u32 Mtot = mM > (u32)GKH_CAP ? (u32)GKH_CAP : mM;
        for (int i = tid; i < (int)Mtot; i += 1024) {
            u64 k = gkB[i];
            u32 bn = (u32)(k >> 48);
            u32 st = histoffs[bn], en = histoffs[bn + 1];
            if (en > (u32)GKH_CAP) en = (u32)GKH_CAP;
            u32 rr = st;
            for (u32 t = st; t < en; ++t) rr += (gkB[t] < k) ? 1u : 0u;
            if (rr < (u32)PRE_NMS_N) {
                u32 idx = (u32)(k & 0xFFFFu);
                sboxes[rr] = bbox[idx];   // appended => bin<2048 => score>=0.75 => valid
            }
        }
        // top-6000 provably all valid -> irem is the pad-only constant
        if (tid < 93) iremL[tid] = 0ull;
        if (tid == 93) iremL[93] = 0xFFFF000000000000ull;  // ranks 6000..6015 removed
    } else {
        // ---- exact fallback: full 8192-bin path over all keys (R8-proven) ----
        for (int b = tid; b < NBINS_F; b += 1024) { histF[b] = 0u; cntF[b] = 0u; }
        __syncthreads();
        for (int i = tid; i < N_ANCH; i += 1024)
            atomicAdd(&histF[(u32)(keys[i] >> 48)], 1u);
        __syncthreads();
        u32 loc[8]; u32 s = 0;
        int base8 = tid * 8;
#pragma unroll
        for (int t = 0; t < 8; ++t) { loc[t] = histF[base8 + t]; s += loc[t]; }
        psum[tid] = s;
        __syncthreads();
        for (int off = 1; off < 1024; off <<= 1) {
            u32 v = (tid >= off) ? psum[tid - off] : 0u;
            __syncthreads();
            psum[tid] += v;
            __syncthreads();
        }
        u32 incl = psum[tid], excl = incl - s;
        u32 run = excl;
#pragma unroll
        for (int t = 0; t < 8; ++t) { histF[base8 + t] = run; run += loc[t]; }
        if (tid == 1023) offs_top = incl;
        if (excl < (u32)PRE_NMS_N && incl >= (u32)PRE_NMS_N) {
            u32 c = excl;
#pragma unroll
            for (int t = 0; t < 8; ++t) {
                if (c + loc[t] >= (u32)PRE_NMS_N) { mB = (u32)(base8 + t); mM = c + loc[t]; break; }
                c += loc[t];
            }
        }
        __syncthreads();
        u32 B = mB;
        for (int i = tid; i < N_ANCH; i += 1024) {
            u64 k = keys[i];
            u32 bn = (u32)(k >> 48);
            if (bn <= B) {
                u32 p = histF[bn] + atomicAdd(&cntF[bn], 1u);
                if (p < (u32)GKH_CAP) gkB[p] = k;
            }
        }
        __syncthreads();
        u32 Mtot = mM > (u32)GKH_CAP ? (u32)GKH_CAP : mM;
        for (int i = tid; i < (int)Mtot; i += 1024) {
            u64 k = gkB[i];
            u32 bn = (u32)(k >> 48);
            u32 st = histF[bn];
            u32 en = (bn + 1 < (u32)NBINS_F) ? histF[bn + 1] : offs_top;
            if (en > (u32)GKH_CAP) en = (u32)GKH_CAP;
            u32 rr = st;
            for (u32 t = st; t < en; ++t) rr += (gkB[t] < k) ? 1u : 0u;
            if (rr < (u32)PRE_NMS_N) {
                u32 idx = (u32)(k & 0xFFFFu);
                float4 b = bbox[idx];
                sboxes[rr] = b;
                bool valid = (b.z - b.x >= 16.0f) && (b.w - b.y >= 16.0f);
                if (valid) atomicAnd(&iremL[rr >> 6], ~(1ull << (rr & 63)));
            }
        }
    }
    __syncthreads();
    if (tid < NWORDS) irem[tid] = iremL[tid];
}

// ===== K_EAGER: rows {b, b+256} x words row>>6..7 -> word-major Mcol. No LDS. =====
__global__ __launch_bounds__(64) void k_eager(const float4* __restrict__ sboxes,
                                              u64* __restrict__ Mcol) {
    int lane = threadIdx.x;
#pragma unroll
    for (int t = 0; t < 2; ++t) {
        int i = blockIdx.x + (t << 8);     // < 512
        float4 bi = sboxes[i];
        for (int w = i >> 6; w < S_WORDS; ++w) {
            int j = (w << 6) + lane;       // < 512
            bool sup = (j > i) && iou_gt(bi, sboxes[j]);
            u64 m = __ballot(sup);
            if (lane == 0) Mcol[w * S_ROWS + i] = m;
        }
    }
}

// ===== K_REDUCE: single wave; coalesced stage + wholesale-word reduce.
//       Deep fallback (words >= 8) reads global sboxes directly. =====
__global__ __launch_bounds__(64) void k_reduce(const float4* __restrict__ sboxes,
                                               const u64* __restrict__ irem,
                                               const u64* __restrict__ Mcol,
                                               float* __restrict__ out) {
    __shared__ u64 S[S_WORDS * S_ROWS];    // 32768 B == Mcol layout
    __shared__ u64 kmaskLDS[NWORDS];
    __shared__ u32 kbaseLDS[NWORDS];
    int lane = threadIdx.x;

    for (int idx = lane; idx < S_WORDS * S_ROWS; idx += 64)
        S[idx] = Mcol[idx];                // coalesced: S layout == Mcol layout
    __syncthreads();
    u64 lanebit = 1ull << lane;
    u64 riem0 = irem[lane];
    u64 riem1 = (lane < NWORDS - 64) ? irem[64 + lane] : ~0ull;

    int kc = 0, wend = 0;
    for (int w = 0; w < NWORDS && kc < POST_NMS_N; ++w) {
        int q0 = w << 6;
        u64 avail, myrow;

        if (w < S_WORDS) {
            u64 add = 0;
            for (int wp = 0; wp < w; ++wp) {
                u64 km = kmaskLDS[wp];
                if (km & lanebit) add |= S[w * S_ROWS + (wp << 6) + lane];
            }
            if (w) {
#pragma unroll
                for (int off = 32; off >= 1; off >>= 1) add |= __shfl_xor(add, off, 64);
            }
            u64 iw = readlane_u64(riem0, w);
            avail = ~(iw | add);
            u64 diag = S[w * S_ROWS + q0 + lane];
            bool ina = (avail >> lane) & 1ull;
            myrow = ina ? (diag & avail) : 0ull;
        } else {
            // exact on-the-fly fallback (only if >212 of first 512 suppressed);
            // performance-irrelevant never-path, reads global sboxes
            int j = q0 + lane; if (j >= PRE_NMS_N) j = PRE_NMS_N - 1;
            float4 bj = sboxes[j];
            bool sup = false;
            for (int wp = 0; wp < w; ++wp) {
                u64 km = kmaskLDS[wp];
                while (km) {
                    int b = __ffsll((unsigned long long)km) - 1; km &= km - 1;
                    sup = sup || iou_gt(sboxes[(wp << 6) + b], bj);
                }
            }
            u64 iw = (w < 64) ? readlane_u64(riem0, w) : readlane_u64(riem1, w - 64);
            avail = ~(iw | __ballot(sup));
            int irow = q0 + lane;
            bool rowok = (irow < PRE_NMS_N) && ((avail >> lane) & 1ull);
            float4 bi2 = sboxes[rowok ? irow : 0];
            u64 my = 0;
            for (int m2 = lane + 1; m2 < 64; ++m2) {
                int jj = q0 + m2;
                if (jj >= PRE_NMS_N) break;
                if (iou_gt(bi2, sboxes[jj])) my |= (1ull << m2);
            }
            myrow = rowok ? (my & avail) : 0ull;
        }

        u64 src = __ballot(myrow != 0ull);
        u64 tor = myrow;
#pragma unroll
        for (int off = 32; off >= 1; off >>= 1) tor |= __shfl_xor(tor, off, 64);
        u64 active = (src | tor) & avail;

        u64 rm = 0;
        while (active) {
            int b = __ffsll((unsigned long long)active) - 1;
            active &= active - 1;
            if (!((rm >> b) & 1ull)) rm |= readlane_u64(myrow, b);
        }
        u64 keptw = avail & ~rm;

        if (lane == 0) { kmaskLDS[w] = keptw; kbaseLDS[w] = (u32)kc; }
        kc += __popcll(keptw);
        wend = w + 1;
    }

    int nout = kc < POST_NMS_N ? kc : POST_NMS_N;
    for (int r2 = lane; r2 < POST_NMS_N; r2 += 64) {
        float4 v = make_float4(0.0f, 0.0f, 0.0f, 0.0f);
        if (r2 < nout) {
            int w = 0;
            while (w + 1 < wend && (int)kbaseLDS[w + 1] <= r2) ++w;
            int n = r2 - (int)kbaseLDS[w];
            int idx = (w << 6) + nth_set_bit(kmaskLDS[w], n);
            v = sboxes[idx];
        }
        ((float4*)out)[r2] = v;
    }
}

extern "C" void kernel_launch(void* const* d_in, const int* in_sizes, int n_in,
                              void* d_out, int out_size, void* d_ws, size_t ws_size,
                              hipStream_t stream) {
    const float4* anchors = (const float4*)d_in[0];
    const float*  cls     = (const float*)d_in[1];
    const float4* reg     = (const float4*)d_in[2];
    const int*    img_w   = (const int*)d_in[3];
    const int*    img_h   = (const int*)d_in[4];

    char* ws = (char*)d_ws;
    float4* bbox   = (float4*)(ws + OFF_BBOX);
    u64*    keys   = (u64*)   (ws + OFF_KEYS);
    float4* sboxes = (float4*)(ws + OFF_SBOX);
    u64*    irem   = (u64*)   (ws + OFF_IREM);
    u32*    bcnt   = (u32*)   (ws + OFF_BCNT);
    u64*    gkraw  = (u64*)   (ws + OFF_GKRAW);
    u64*    Mcol   = (u64*)   (ws + OFF_MCOL);

    // Fence-free pipeline: kernel boundaries provide cross-XCD visibility.
    k_decode<<<dim3(GRID_A), dim3(1024), 0, stream>>>(
        anchors, cls, reg, img_w, img_h, bbox, keys, gkraw, bcnt);
    k_select<<<dim3(1), dim3(1024), 0, stream>>>(
        keys, gkraw, bcnt, bbox, sboxes, irem);
    k_eager<<<dim3(GRID_B), dim3(64), 0, stream>>>(sboxes, Mcol);
    k_reduce<<<dim3(1), dim3(64), 0, stream>>>(
        sboxes, irem, Mcol, (float*)d_out);
}

// Round 19
// 46.855 us; speedup vs baseline: 2.0111x; 1.2753x over previous
//
#include <hip/hip_runtime.h>
#include <stdint.h>

typedef unsigned long long u64;
typedef unsigned int u32;

#define N_ANCH     36864
#define PRE_NMS_N  6000
#define POST_NMS_N 300
#define NBINS_F    8192     // fallback full bin count
#define NBINS_H    2048     // happy-path bins == prefilter width
#define PF_BIN     2048     // append keys with bin < 2048 (score >= 0.75): E=8018 >> 6000
#define SEG_CAP    448      // per-block segment cap (E=223, ~15 sigma)
#define GKH_CAP    8192
#define NWORDS     94       // ceil(6000/64)
#define S_WORDS    8        // eager words (candidates 0..511)
#define S_ROWS     512
#define GRID_A     36       // 36 x 1024 == N_ANCH
#define GRID_B     256      // rows {b, b+256} per block

// ---- workspace layout (bytes) ----
#define OFF_BBOX   0            // float4 bbox[36864]       589824
#define OFF_KEYS   589824       // u64 keys[36864]          294912 (fallback only)
#define OFF_SBOX   884736       // float4 sboxes[6000]       96000
#define OFF_IREM   980736       // u64 irem[94]                752
#define OFF_BCNT   981488       // u32 bcnt[36]                144
#define OFF_GKRAW  981648       // u64 gkraw[36*448]        129024
#define OFF_MCOL   1110672      // u64 Mcol[8*512]           32768 (word-major)
#define WS_FULL    (OFF_MCOL + (size_t)S_WORDS * S_ROWS * 8)

// Value-uniform monotone bin: higher score -> lower bin.
__device__ __forceinline__ u32 score_bin(float s) {
    float v = fminf(fmaxf(s, 0.0f), 1.0f);
    u32 q = (u32)(v * 8192.0f);
    if (q > 8191u) q = 8191u;
    return 8191u - q;
}

// key = bin(16) | sortable_score(32) | idx(16); ascending u64 ==
// (score desc, idx asc) exactly (bin monotone in score).
__device__ __forceinline__ u64 make_key(float s, u32 bin, u32 idx) {
    u32 u = __float_as_uint(s);
    u32 sortable = u ^ ((u >> 31) ? 0xFFFFFFFFu : 0x80000000u);
    u32 hi = ~sortable;
    return ((u64)bin << 48) | ((u64)hi << 16) | (u64)idx;
}

__device__ __forceinline__ u64 readlane_u64(u64 v, int l) {
    u32 lo = __builtin_amdgcn_readlane((u32)(v & 0xFFFFFFFFull), l);
    u32 hi = __builtin_amdgcn_readlane((u32)(v >> 32), l);
    return ((u64)hi << 32) | (u64)lo;
}

__device__ __forceinline__ int nth_set_bit(u64 m, int n) {
    int pos = 0;
    u32 c = __popc((u32)m);
    if ((u32)n >= c) { n -= c; pos = 32; m >>= 32; }
    u32 x = (u32)m;
    c = __popc(x & 0xFFFFu);
    if ((u32)n >= c) { n -= c; pos += 16; x >>= 16; }
    c = __popc(x & 0xFFu);
    if ((u32)n >= c) { n -= c; pos += 8; x >>= 8; }
    c = __popc(x & 0xFu);
    if ((u32)n >= c) { n -= c; pos += 4; x >>= 4; }
    c = __popc(x & 0x3u);
    if ((u32)n >= c) { n -= c; pos += 2; x >>= 2; }
    c = x & 1u;
    if ((u32)n >= c) { pos += 1; }
    return pos;
}

// EXACT reference IoU decision (identical expression tree to all prior rounds)
__device__ __forceinline__ bool iou_gt(float4 a, float4 b) {
    float aa = (a.z - a.x) * (a.w - a.y);
    float ab = (b.z - b.x) * (b.w - b.y);
    float xx1 = fmaxf(a.x, b.x), yy1 = fmaxf(a.y, b.y);
    float xx2 = fminf(a.z, b.z), yy2 = fminf(a.w, b.w);
    float inter = fmaxf(xx2 - xx1, 0.0f) * fmaxf(yy2 - yy1, 0.0f);
    float iou = inter / (aa + ab - inter + 1e-9f);
    return iou > 0.7f;
}

// ===== K_DECODE: decode + segmented coalesced append (VERBATIM R18). =====
__global__ __launch_bounds__(1024) void k_decode(const float4* __restrict__ anchors,
                                                 const float* __restrict__ cls,
                                                 const float4* __restrict__ reg,
                                                 const int* __restrict__ img_w,
                                                 const int* __restrict__ img_h,
                                                 float4* __restrict__ bbox,
                                                 u64* __restrict__ keys,
                                                 u64* __restrict__ gkraw,
                                                 u32* __restrict__ bcnt) {
    __shared__ u32 blkCnt;
    int tid = threadIdx.x, lane = tid & 63;
    int gi = blockIdx.x * 1024 + tid;      // exact: 36*1024 == N_ANCH

    if (tid == 0) blkCnt = 0u;
    __syncthreads();

    float4 a = anchors[gi];
    float4 r = reg[gi];
    float w  = a.z - a.x, h = a.w - a.y;
    float cx = a.x + 0.5f * w, cy = a.y + 0.5f * h;
    float pcx = r.x * w + cx, pcy = r.y * h + cy;
    float pw = expf(r.z) * w,  ph = expf(r.w) * h;
    float b0 = pcx - 0.5f * pw, b1 = pcy - 0.5f * ph;
    float b2 = pcx + 0.5f * pw, b3 = pcy + 0.5f * ph;

    float fh = (float)img_h[0], fw = (float)img_w[0];
    // reference: cols 0,2 clipped to [0, img_h]; cols 1,3 to [0, img_w]
    b0 = fminf(fmaxf(b0, 0.0f), fh);
    b2 = fminf(fmaxf(b2, 0.0f), fh);
    b1 = fminf(fmaxf(b1, 0.0f), fw);
    b3 = fminf(fmaxf(b3, 0.0f), fw);

    bool valid = (b2 - b0 >= 16.0f) && (b3 - b1 >= 16.0f);
    float score = valid ? cls[gi] : -1e9f;

    bbox[gi] = make_float4(b0, b1, b2, b3);
    u32 bin = score_bin(score);
    u64 key = make_key(score, bin, (u32)gi);
    keys[gi] = key;

    bool qf = bin < (u32)PF_BIN;
    u64 ball = __ballot(qf);
    u32 n = (u32)__popcll(ball);
    u32 wbase = 0;
    if (lane == 0 && n) wbase = atomicAdd(&blkCnt, n);
    wbase = (u32)__shfl((int)wbase, 0, 64);
    if (qf) {
        u32 pos = wbase + (u32)__popcll(ball & ((1ull << lane) - 1ull));
        if (pos < SEG_CAP) gkraw[(size_t)blockIdx.x * SEG_CAP + pos] = key;
    }

    __syncthreads();
    if (tid == 0) bcnt[blockIdx.x] = blkCnt;
}

// ===== K_SELECT: single block; selection chain -> sboxes + irem (VERBATIM R18). =====
__global__ __launch_bounds__(1024) void k_select(const u64* __restrict__ keys,
                                                 const u64* __restrict__ gkraw,
                                                 const u32* __restrict__ bcnt,
                                                 const float4* __restrict__ bbox,
                                                 float4* __restrict__ sboxes,
                                                 u64* __restrict__ irem) {
    __shared__ u32 histoffs[NBINS_H + 1];
    __shared__ u32 cntH[NBINS_H];
    __shared__ u32 wsum[16];
    __shared__ u64 gkB[GKH_CAP];
    __shared__ u32 psum[1024];
    __shared__ u32 histF[NBINS_F];
    __shared__ u32 cntF[NBINS_F];
    __shared__ u64 iremL[NWORDS];
    __shared__ u32 mB, mM, offs_top;

    int tid = threadIdx.x, lane = tid & 63, wave = tid >> 6;

    if (tid < NWORDS) iremL[tid] = ~0ull;

    u32 count = 0; bool ovf = false;
    for (int b = 0; b < GRID_A; ++b) {
        u32 c = bcnt[b];
        count += c;
        ovf = ovf || (c > (u32)SEG_CAP);
    }
    bool happy = (count >= (u32)PRE_NMS_N) && !ovf;

    if (happy) {
        for (int b = tid; b < NBINS_H; b += 1024) { histoffs[b] = 0u; cntH[b] = 0u; }
        __syncthreads();
        for (int i = tid; i < GRID_A * SEG_CAP; i += 1024) {
            int b = i / SEG_CAP, o = i - b * SEG_CAP;
            if (o < (int)bcnt[b])
                atomicAdd(&histoffs[(u32)(gkraw[i] >> 48)], 1u);
        }
        __syncthreads();

        u32 l0 = histoffs[2 * tid], l1 = histoffs[2 * tid + 1];
        u32 s = l0 + l1;
        u32 incv = s;
#pragma unroll
        for (int off = 1; off < 64; off <<= 1) {
            u32 v = (u32)__shfl_up((int)incv, off, 64);
            if (lane >= off) incv += v;
        }
        if (lane == 63) wsum[wave] = incv;
        __syncthreads();
        if (tid == 0) {
            u32 run = 0;
#pragma unroll
            for (int k2 = 0; k2 < 16; ++k2) { u32 t2 = wsum[k2]; wsum[k2] = run; run += t2; }
        }
        __syncthreads();
        u32 incl = wsum[wave] + incv;
        u32 excl = incl - s;
        histoffs[2 * tid] = excl;
        histoffs[2 * tid + 1] = excl + l0;
        if (tid == 1023) histoffs[NBINS_H] = incl;
        if (excl < (u32)PRE_NMS_N && incl >= (u32)PRE_NMS_N) {
            if (excl + l0 >= (u32)PRE_NMS_N) { mB = 2 * tid;     mM = excl + l0; }
            else                             { mB = 2 * tid + 1; mM = incl; }
        }
        __syncthreads();

        u32 B = mB;
        for (int i = tid; i < GRID_A * SEG_CAP; i += 1024) {
            int b = i / SEG_CAP, o = i - b * SEG_CAP;
            if (o < (int)bcnt[b]) {
                u64 k = gkraw[i];
                u32 bn = (u32)(k >> 48);
                if (bn <= B) {
                    u32 p = histoffs[bn] + atomicAdd(&cntH[bn], 1u);
                    if (p < (u32)GKH_CAP) gkB[p] = k;
                }
            }
        }
        __syncthreads();
        u32 Mtot = mM > (u32)GKH_CAP ? (u32)GKH_CAP : mM;
        for (int i = tid; i < (int)Mtot; i += 1024) {
            u64 k = gkB[i];
            u32 bn = (u32)(k >> 48);
            u32 st = histoffs[bn], en = histoffs[bn + 1];
            if (en > (u32)GKH_CAP) en = (u32)GKH_CAP;
            u32 rr = st;
            for (u32 t = st; t < en; ++t) rr += (gkB[t] < k) ? 1u : 0u;
            if (rr < (u32)PRE_NMS_N) {
                u32 idx = (u32)(k & 0xFFFFu);
                sboxes[rr] = bbox[idx];   // appended => bin<2048 => score>=0.75 => valid
            }
        }
        if (tid < 93) iremL[tid] = 0ull;
        if (tid == 93) iremL[93] = 0xFFFF000000000000ull;
    } else {
        // ---- exact fallback: full 8192-bin path over all keys (R8-proven) ----
        for (int b = tid; b < NBINS_F; b += 1024) { histF[b] = 0u; cntF[b] = 0u; }
        __syncthreads();
        for (int i = tid; i < N_ANCH; i += 1024)
            atomicAdd(&histF[(u32)(keys[i] >> 48)], 1u);
        __syncthreads();
        u32 loc[8]; u32 s = 0;
        int base8 = tid * 8;
#pragma unroll
        for (int t = 0; t < 8; ++t) { loc[t] = histF[base8 + t]; s += loc[t]; }
        psum[tid] = s;
        __syncthreads();
        for (int off = 1; off < 1024; off <<= 1) {
            u32 v = (tid >= off) ? psum[tid - off] : 0u;
            __syncthreads();
            psum[tid] += v;
            __syncthreads();
        }
        u32 incl = psum[tid], excl = incl - s;
        u32 run = excl;
#pragma unroll
        for (int t = 0; t < 8; ++t) { histF[base8 + t] = run; run += loc[t]; }
        if (tid == 1023) offs_top = incl;
        if (excl < (u32)PRE_NMS_N && incl >= (u32)PRE_NMS_N) {
            u32 c = excl;
#pragma unroll
            for (int t = 0; t < 8; ++t) {
                if (c + loc[t] >= (u32)PRE_NMS_N) { mB = (u32)(base8 + t); mM = c + loc[t]; break; }
                c += loc[t];
            }
        }
        __syncthreads();
        u32 B = mB;
        for (int i = tid; i < N_ANCH; i += 1024) {
            u64 k = keys[i];
            u32 bn = (u32)(k >> 48);
            if (bn <= B) {
                u32 p = histF[bn] + atomicAdd(&cntF[bn], 1u);
                if (p < (u32)GKH_CAP) gkB[p] = k;
            }
        }
        __syncthreads();
        u32 Mtot = mM > (u32)GKH_CAP ? (u32)GKH_CAP : mM;
        for (int i = tid; i < (int)Mtot; i += 1024) {
            u64 k = gkB[i];
            u32 bn = (u32)(k >> 48);
            u32 st = histF[bn];
            u32 en = (bn + 1 < (u32)NBINS_F) ? histF[bn + 1] : offs_top;
            if (en > (u32)GKH_CAP) en = (u32)GKH_CAP;
            u32 rr = st;
            for (u32 t = st; t < en; ++t) rr += (gkB[t] < k) ? 1u : 0u;
            if (rr < (u32)PRE_NMS_N) {
                u32 idx = (u32)(k & 0xFFFFu);
                float4 b = bbox[idx];
                sboxes[rr] = b;
                bool valid = (b.z - b.x >= 16.0f) && (b.w - b.y >= 16.0f);
                if (valid) atomicAnd(&iremL[rr >> 6], ~(1ull << (rr & 63)));
            }
        }
    }
    __syncthreads();
    if (tid < NWORDS) irem[tid] = iremL[tid];
}

// ===== K_EAGER: 128 threads/block -- wave t owns row b + t*256 (2x TLP). =====
__global__ __launch_bounds__(128) void k_eager(const float4* __restrict__ sboxes,
                                               u64* __restrict__ Mcol) {
    int lane = threadIdx.x & 63, t = threadIdx.x >> 6;
    int i = blockIdx.x + (t << 8);         // < 512
    float4 bi = sboxes[i];
    for (int w = i >> 6; w < S_WORDS; ++w) {
        int j = (w << 6) + lane;           // < 512
        bool sup = (j > i) && iou_gt(bi, sboxes[j]);
        u64 m = __ballot(sup);             // wave-local
        if (lane == 0) Mcol[w * S_ROWS + i] = m;
    }
}

// ===== K_REDUCE: 1024 threads stage S cooperatively (16 waves of outstanding
//       loads -> hides cold L2/HBM latency); wave 0 then runs the serial scan. =====
__global__ __launch_bounds__(1024) void k_reduce(const float4* __restrict__ sboxes,
                                                 const u64* __restrict__ irem,
                                                 const u64* __restrict__ Mcol,
                                                 float* __restrict__ out) {
    __shared__ u64 S[S_WORDS * S_ROWS];    // 32768 B == Mcol layout
    __shared__ u64 kmaskLDS[NWORDS];
    __shared__ u32 kbaseLDS[NWORDS];
    int tid = threadIdx.x, lane = tid & 63;

    for (int idx = tid; idx < S_WORDS * S_ROWS; idx += 1024)
        S[idx] = Mcol[idx];                // coalesced, 16-wave TLP
    __syncthreads();
    if (tid >= 64) return;                 // wave 0 continues alone (no barriers below)

    u64 lanebit = 1ull << lane;
    u64 riem0 = irem[lane];
    u64 riem1 = (lane < NWORDS - 64) ? irem[64 + lane] : ~0ull;

    int kc = 0, wend = 0;
    for (int w = 0; w < NWORDS && kc < POST_NMS_N; ++w) {
        int q0 = w << 6;
        u64 avail, myrow;

        if (w < S_WORDS) {
            u64 add = 0;
            for (int wp = 0; wp < w; ++wp) {
                u64 km = kmaskLDS[wp];
                if (km & lanebit) add |= S[w * S_ROWS + (wp << 6) + lane];
            }
            if (w) {
#pragma unroll
                for (int off = 32; off >= 1; off >>= 1) add |= __shfl_xor(add, off, 64);
            }
            u64 iw = readlane_u64(riem0, w);
            avail = ~(iw | add);
            u64 diag = S[w * S_ROWS + q0 + lane];
            bool ina = (avail >> lane) & 1ull;
            myrow = ina ? (diag & avail) : 0ull;
        } else {
            // exact on-the-fly fallback (only if >212 of first 512 suppressed);
            // performance-irrelevant never-path, reads global sboxes
            int j = q0 + lane; if (j >= PRE_NMS_N) j = PRE_NMS_N - 1;
            float4 bj = sboxes[j];
            bool sup = false;
            for (int wp = 0; wp < w; ++wp) {
                u64 km = kmaskLDS[wp];
                while (km) {
                    int b = __ffsll((unsigned long long)km) - 1; km &= km - 1;
                    sup = sup || iou_gt(sboxes[(wp << 6) + b], bj);
                }
            }
            u64 iw = (w < 64) ? readlane_u64(riem0, w) : readlane_u64(riem1, w - 64);
            avail = ~(iw | __ballot(sup));
            int irow = q0 + lane;
            bool rowok = (irow < PRE_NMS_N) && ((avail >> lane) & 1ull);
            float4 bi2 = sboxes[rowok ? irow : 0];
            u64 my = 0;
            for (int m2 = lane + 1; m2 < 64; ++m2) {
                int jj = q0 + m2;
                if (jj >= PRE_NMS_N) break;
                if (iou_gt(bi2, sboxes[jj])) my |= (1ull << m2);
            }
            myrow = rowok ? (my & avail) : 0ull;
        }

        u64 src = __ballot(myrow != 0ull);
        u64 tor = myrow;
#pragma unroll
        for (int off = 32; off >= 1; off >>= 1) tor |= __shfl_xor(tor, off, 64);
        u64 active = (src | tor) & avail;

        u64 rm = 0;
        while (active) {
            int b = __ffsll((unsigned long long)active) - 1;
            active &= active - 1;
            if (!((rm >> b) & 1ull)) rm |= readlane_u64(myrow, b);
        }
        u64 keptw = avail & ~rm;

        if (lane == 0) { kmaskLDS[w] = keptw; kbaseLDS[w] = (u32)kc; }
        kc += __popcll(keptw);
        wend = w + 1;
    }

    int nout = kc < POST_NMS_N ? kc : POST_NMS_N;
    for (int r2 = lane; r2 < POST_NMS_N; r2 += 64) {
        float4 v = make_float4(0.0f, 0.0f, 0.0f, 0.0f);
        if (r2 < nout) {
            int w = 0;
            while (w + 1 < wend && (int)kbaseLDS[w + 1] <= r2) ++w;
            int n = r2 - (int)kbaseLDS[w];
            int idx = (w << 6) + nth_set_bit(kmaskLDS[w], n);
            v = sboxes[idx];
        }
        ((float4*)out)[r2] = v;
    }
}

extern "C" void kernel_launch(void* const* d_in, const int* in_sizes, int n_in,
                              void* d_out, int out_size, void* d_ws, size_t ws_size,
                              hipStream_t stream) {
    const float4* anchors = (const float4*)d_in[0];
    const float*  cls     = (const float*)d_in[1];
    const float4* reg     = (const float4*)d_in[2];
    const int*    img_w   = (const int*)d_in[3];
    const int*    img_h   = (const int*)d_in[4];

    char* ws = (char*)d_ws;
    float4* bbox   = (float4*)(ws + OFF_BBOX);
    u64*    keys   = (u64*)   (ws + OFF_KEYS);
    float4* sboxes = (float4*)(ws + OFF_SBOX);
    u64*    irem   = (u64*)   (ws + OFF_IREM);
    u32*    bcnt   = (u32*)   (ws + OFF_BCNT);
    u64*    gkraw  = (u64*)   (ws + OFF_GKRAW);
    u64*    Mcol   = (u64*)   (ws + OFF_MCOL);

    k_decode<<<dim3(GRID_A), dim3(1024), 0, stream>>>(
        anchors, cls, reg, img_w, img_h, bbox, keys, gkraw, bcnt);
    k_select<<<dim3(1), dim3(1024), 0, stream>>>(
        keys, gkraw, bcnt, bbox, sboxes, irem);
    k_eager<<<dim3(GRID_B), dim3(128), 0, stream>>>(sboxes, Mcol);
    k_reduce<<<dim3(1), dim3(1024), 0, stream>>>(
        sboxes, irem, Mcol, (float*)d_out);
}

// Round 20
// 42.872 us; speedup vs baseline: 2.1979x; 1.0929x over previous
//
#include <hip/hip_runtime.h>
#include <stdint.h>

typedef unsigned long long u64;
typedef unsigned int u32;

#define N_ANCH     36864
#define PRE_NMS_N  6000
#define POST_NMS_N 300
#define NBINS_F    8192     // fallback full bin count
#define NBINS_H    2048     // happy-path bins == prefilter width
#define PF_BIN     2048     // append keys with bin < 2048 (score >= 0.75): E=8018 >> 6000
#define SEG_CAP    112      // per-block segment cap (E=55.7, ~2x mean, P(ovf)~5e-8)
#define GKH_CAP    8192
#define NWORDS     94       // ceil(6000/64)
#define S_WORDS    8        // eager words (candidates 0..511)
#define S_ROWS     512
#define GRID_A     144      // 144 x 256 == N_ANCH (4x more CUs than 36x1024)
#define BLK_A      256
#define NSEG_TOT   (GRID_A * SEG_CAP)   // 16128
#define GRID_B     256      // rows {b, b+256} per block

// ---- workspace layout (bytes) ----
#define OFF_BBOX   0            // float4 bbox[36864]       589824
#define OFF_KEYS   589824       // u64 keys[36864]          294912 (fallback only)
#define OFF_SBOX   884736       // float4 sboxes[6000]       96000
#define OFF_IREM   980736       // u64 irem[94]                752
#define OFF_BCNT   981488       // u32 bcnt[144]               576
#define OFF_GKRAW  982064       // u64 gkraw[144*112]       129024
#define OFF_MCOL   1111088      // u64 Mcol[8*512]           32768 (word-major)
#define WS_FULL    (OFF_MCOL + (size_t)S_WORDS * S_ROWS * 8)

// Value-uniform monotone bin: higher score -> lower bin.
__device__ __forceinline__ u32 score_bin(float s) {
    float v = fminf(fmaxf(s, 0.0f), 1.0f);
    u32 q = (u32)(v * 8192.0f);
    if (q > 8191u) q = 8191u;
    return 8191u - q;
}

// key = bin(16) | sortable_score(32) | idx(16); ascending u64 ==
// (score desc, idx asc) exactly (bin monotone in score).
__device__ __forceinline__ u64 make_key(float s, u32 bin, u32 idx) {
    u32 u = __float_as_uint(s);
    u32 sortable = u ^ ((u >> 31) ? 0xFFFFFFFFu : 0x80000000u);
    u32 hi = ~sortable;
    return ((u64)bin << 48) | ((u64)hi << 16) | (u64)idx;
}

__device__ __forceinline__ u64 readlane_u64(u64 v, int l) {
    u32 lo = __builtin_amdgcn_readlane((u32)(v & 0xFFFFFFFFull), l);
    u32 hi = __builtin_amdgcn_readlane((u32)(v >> 32), l);
    return ((u64)hi << 32) | (u64)lo;
}

__device__ __forceinline__ int nth_set_bit(u64 m, int n) {
    int pos = 0;
    u32 c = __popc((u32)m);
    if ((u32)n >= c) { n -= c; pos = 32; m >>= 32; }
    u32 x = (u32)m;
    c = __popc(x & 0xFFFFu);
    if ((u32)n >= c) { n -= c; pos += 16; x >>= 16; }
    c = __popc(x & 0xFFu);
    if ((u32)n >= c) { n -= c; pos += 8; x >>= 8; }
    c = __popc(x & 0xFu);
    if ((u32)n >= c) { n -= c; pos += 4; x >>= 4; }
    c = __popc(x & 0x3u);
    if ((u32)n >= c) { n -= c; pos += 2; x >>= 2; }
    c = x & 1u;
    if ((u32)n >= c) { pos += 1; }
    return pos;
}

// EXACT reference IoU decision (identical expression tree to all prior rounds)
__device__ __forceinline__ bool iou_gt(float4 a, float4 b) {
    float aa = (a.z - a.x) * (a.w - a.y);
    float ab = (b.z - b.x) * (b.w - b.y);
    float xx1 = fmaxf(a.x, b.x), yy1 = fmaxf(a.y, b.y);
    float xx2 = fminf(a.z, b.z), yy2 = fminf(a.w, b.w);
    float inter = fmaxf(xx2 - xx1, 0.0f) * fmaxf(yy2 - yy1, 0.0f);
    float iou = inter / (aa + ab - inter + 1e-9f);
    return iou > 0.7f;
}

// ===== K_DECODE: 144 x 256 (4x CU coverage vs 36x1024); decode + segmented
//       coalesced append. No fences, no global atomics. =====
__global__ __launch_bounds__(BLK_A) void k_decode(const float4* __restrict__ anchors,
                                                  const float* __restrict__ cls,
                                                  const float4* __restrict__ reg,
                                                  const int* __restrict__ img_w,
                                                  const int* __restrict__ img_h,
                                                  float4* __restrict__ bbox,
                                                  u64* __restrict__ keys,
                                                  u64* __restrict__ gkraw,
                                                  u32* __restrict__ bcnt) {
    __shared__ u32 blkCnt;
    int tid = threadIdx.x, lane = tid & 63;
    int gi = blockIdx.x * BLK_A + tid;     // exact: 144*256 == N_ANCH

    if (tid == 0) blkCnt = 0u;
    __syncthreads();

    float4 a = anchors[gi];
    float4 r = reg[gi];
    float w  = a.z - a.x, h = a.w - a.y;
    float cx = a.x + 0.5f * w, cy = a.y + 0.5f * h;
    float pcx = r.x * w + cx, pcy = r.y * h + cy;
    float pw = expf(r.z) * w,  ph = expf(r.w) * h;
    float b0 = pcx - 0.5f * pw, b1 = pcy - 0.5f * ph;
    float b2 = pcx + 0.5f * pw, b3 = pcy + 0.5f * ph;

    float fh = (float)img_h[0], fw = (float)img_w[0];
    // reference: cols 0,2 clipped to [0, img_h]; cols 1,3 to [0, img_w]
    b0 = fminf(fmaxf(b0, 0.0f), fh);
    b2 = fminf(fmaxf(b2, 0.0f), fh);
    b1 = fminf(fmaxf(b1, 0.0f), fw);
    b3 = fminf(fmaxf(b3, 0.0f), fw);

    bool valid = (b2 - b0 >= 16.0f) && (b3 - b1 >= 16.0f);
    float score = valid ? cls[gi] : -1e9f;

    bbox[gi] = make_float4(b0, b1, b2, b3);
    u32 bin = score_bin(score);
    u64 key = make_key(score, bin, (u32)gi);
    keys[gi] = key;

    bool qf = bin < (u32)PF_BIN;
    u64 ball = __ballot(qf);
    u32 n = (u32)__popcll(ball);
    u32 wbase = 0;
    if (lane == 0 && n) wbase = atomicAdd(&blkCnt, n);
    wbase = (u32)__shfl((int)wbase, 0, 64);
    if (qf) {
        u32 pos = wbase + (u32)__popcll(ball & ((1ull << lane) - 1ull));
        if (pos < SEG_CAP) gkraw[(size_t)blockIdx.x * SEG_CAP + pos] = key;
    }

    __syncthreads();
    if (tid == 0) bcnt[blockIdx.x] = blkCnt;
}

// ===== K_SELECT: single block. gkraw register-cached ONCE (16 u64/thread,
//       static unroll) -> hist and scatter run from registers (1 global pass). =====
__global__ __launch_bounds__(1024) void k_select(const u64* __restrict__ keys,
                                                 const u64* __restrict__ gkraw,
                                                 const u32* __restrict__ bcnt,
                                                 const float4* __restrict__ bbox,
                                                 float4* __restrict__ sboxes,
                                                 u64* __restrict__ irem) {
    __shared__ u32 histoffs[NBINS_H + 1];
    __shared__ u32 cntH[NBINS_H];
    __shared__ u32 wsum[16];
    __shared__ u64 gkB[GKH_CAP];
    __shared__ u32 psum[1024];
    __shared__ u32 histF[NBINS_F];
    __shared__ u32 cntF[NBINS_F];
    __shared__ u64 iremL[NWORDS];
    __shared__ u32 mB, mM, offs_top;

    int tid = threadIdx.x, lane = tid & 63, wave = tid >> 6;

    if (tid < NWORDS) iremL[tid] = ~0ull;

    // ---- register-cache all 16128 gkraw slots (16/thread, static indexing;
    //      loads issued up-front & independent -> latency overlapped) ----
    u64 myk[16];
    u32 vmask = 0;
#pragma unroll
    for (int t = 0; t < 16; ++t) {
        int i = tid + t * 1024;
        int b = i / SEG_CAP, o = i - b * SEG_CAP;
        myk[t] = gkraw[i];                     // unconditional: slot allocated
        if (o < (int)bcnt[b]) vmask |= (1u << t);
    }

    u32 count = 0; bool ovf = false;
    for (int b = 0; b < GRID_A; ++b) {
        u32 c = bcnt[b];
        count += c;
        ovf = ovf || (c > (u32)SEG_CAP);
    }
    bool happy = (count >= (u32)PRE_NMS_N) && !ovf;

    if (happy) {
        // top-6000 subset proof: every non-appended key has bin >= PF_BIN >
        // any appended bin, and count >= 6000 appended keys exist.
        for (int b = tid; b < NBINS_H; b += 1024) { histoffs[b] = 0u; cntH[b] = 0u; }
        __syncthreads();
#pragma unroll
        for (int t = 0; t < 16; ++t)
            if (vmask & (1u << t))
                atomicAdd(&histoffs[(u32)(myk[t] >> 48)], 1u);
        __syncthreads();

        // 2-barrier block scan (shfl wave scan + 16-partial combine)
        u32 l0 = histoffs[2 * tid], l1 = histoffs[2 * tid + 1];
        u32 s = l0 + l1;
        u32 incv = s;
#pragma unroll
        for (int off = 1; off < 64; off <<= 1) {
            u32 v = (u32)__shfl_up((int)incv, off, 64);
            if (lane >= off) incv += v;
        }
        if (lane == 63) wsum[wave] = incv;
        __syncthreads();
        if (tid == 0) {
            u32 run = 0;
#pragma unroll
            for (int k2 = 0; k2 < 16; ++k2) { u32 t2 = wsum[k2]; wsum[k2] = run; run += t2; }
        }
        __syncthreads();
        u32 incl = wsum[wave] + incv;
        u32 excl = incl - s;
        histoffs[2 * tid] = excl;
        histoffs[2 * tid + 1] = excl + l0;
        if (tid == 1023) histoffs[NBINS_H] = incl;
        if (excl < (u32)PRE_NMS_N && incl >= (u32)PRE_NMS_N) {
            if (excl + l0 >= (u32)PRE_NMS_N) { mB = 2 * tid;     mM = excl + l0; }
            else                             { mB = 2 * tid + 1; mM = incl; }
        }
        __syncthreads();

        u32 B = mB;
#pragma unroll
        for (int t = 0; t < 16; ++t) {
            if (vmask & (1u << t)) {
                u64 k = myk[t];
                u32 bn = (u32)(k >> 48);
                if (bn <= B) {
                    u32 p = histoffs[bn] + atomicAdd(&cntH[bn], 1u);
                    if (p < (u32)GKH_CAP) gkB[p] = k;
                }
            }
        }
        __syncthreads();
        u32 Mtot = mM > (u32)GKH_CAP ? (u32)GKH_CAP : mM;
        for (int i = tid; i < (int)Mtot; i += 1024) {
            u64 k = gkB[i];
            u32 bn = (u32)(k >> 48);
            u32 st = histoffs[bn], en = histoffs[bn + 1];
            if (en > (u32)GKH_CAP) en = (u32)GKH_CAP;
            u32 rr = st;
            for (u32 t = st; t < en; ++t) rr += (gkB[t] < k) ? 1u : 0u;
            if (rr < (u32)PRE_NMS_N) {
                u32 idx = (u32)(k & 0xFFFFu);
                sboxes[rr] = bbox[idx];   // appended => bin<2048 => score>=0.75 => valid
            }
        }
        if (tid < 93) iremL[tid] = 0ull;
        if (tid == 93) iremL[93] = 0xFFFF000000000000ull;  // ranks 6000..6015 removed
    } else {
        // ---- exact fallback: full 8192-bin path over all keys (R8-proven) ----
        for (int b = tid; b < NBINS_F; b += 1024) { histF[b] = 0u; cntF[b] = 0u; }
        __syncthreads();
        for (int i = tid; i < N_ANCH; i += 1024)
            atomicAdd(&histF[(u32)(keys[i] >> 48)], 1u);
        __syncthreads();
        u32 loc[8]; u32 s = 0;
        int base8 = tid * 8;
#pragma unroll
        for (int t = 0; t < 8; ++t) { loc[t] = histF[base8 + t]; s += loc[t]; }
        psum[tid] = s;
        __syncthreads();
        for (int off = 1; off < 1024; off <<= 1) {
            u32 v = (tid >= off) ? psum[tid - off] : 0u;
            __syncthreads();
            psum[tid] += v;
            __syncthreads();
        }
        u32 incl = psum[tid], excl = incl - s;
        u32 run = excl;
#pragma unroll
        for (int t = 0; t < 8; ++t) { histF[base8 + t] = run; run += loc[t]; }
        if (tid == 1023) offs_top = incl;
        if (excl < (u32)PRE_NMS_N && incl >= (u32)PRE_NMS_N) {
            u32 c = excl;
#pragma unroll
            for (int t = 0; t < 8; ++t) {
                if (c + loc[t] >= (u32)PRE_NMS_N) { mB = (u32)(base8 + t); mM = c + loc[t]; break; }
                c += loc[t];
            }
        }
        __syncthreads();
        u32 B = mB;
        for (int i = tid; i < N_ANCH; i += 1024) {
            u64 k = keys[i];
            u32 bn = (u32)(k >> 48);
            if (bn <= B) {
                u32 p = histF[bn] + atomicAdd(&cntF[bn], 1u);
                if (p < (u32)GKH_CAP) gkB[p] = k;
            }
        }
        __syncthreads();
        u32 Mtot = mM > (u32)GKH_CAP ? (u32)GKH_CAP : mM;
        for (int i = tid; i < (int)Mtot; i += 1024) {
            u64 k = gkB[i];
            u32 bn = (u32)(k >> 48);
            u32 st = histF[bn];
            u32 en = (bn + 1 < (u32)NBINS_F) ? histF[bn + 1] : offs_top;
            if (en > (u32)GKH_CAP) en = (u32)GKH_CAP;
            u32 rr = st;
            for (u32 t = st; t < en; ++t) rr += (gkB[t] < k) ? 1u : 0u;
            if (rr < (u32)PRE_NMS_N) {
                u32 idx = (u32)(k & 0xFFFFu);
                float4 b = bbox[idx];
                sboxes[rr] = b;
                bool valid = (b.z - b.x >= 16.0f) && (b.w - b.y >= 16.0f);
                if (valid) atomicAnd(&iremL[rr >> 6], ~(1ull << (rr & 63)));
            }
        }
    }
    __syncthreads();
    if (tid < NWORDS) irem[tid] = iremL[tid];
}

// ===== K_EAGER: 128 threads/block -- wave t owns row b + t*256 (VERBATIM R19). =====
__global__ __launch_bounds__(128) void k_eager(const float4* __restrict__ sboxes,
                                               u64* __restrict__ Mcol) {
    int lane = threadIdx.x & 63, t = threadIdx.x >> 6;
    int i = blockIdx.x + (t << 8);         // < 512
    float4 bi = sboxes[i];
    for (int w = i >> 6; w < S_WORDS; ++w) {
        int j = (w << 6) + lane;           // < 512
        bool sup = (j > i) && iou_gt(bi, sboxes[j]);
        u64 m = __ballot(sup);             // wave-local
        if (lane == 0) Mcol[w * S_ROWS + i] = m;
    }
}

// ===== K_REDUCE: 1024-thread cooperative stage + wave-0 serial scan (VERBATIM R19). =====
__global__ __launch_bounds__(1024) void k_reduce(const float4* __restrict__ sboxes,
                                                 const u64* __restrict__ irem,
                                                 const u64* __restrict__ Mcol,
                                                 float* __restrict__ out) {
    __shared__ u64 S[S_WORDS * S_ROWS];    // 32768 B == Mcol layout
    __shared__ u64 kmaskLDS[NWORDS];
    __shared__ u32 kbaseLDS[NWORDS];
    int tid = threadIdx.x, lane = tid & 63;

    for (int idx = tid; idx < S_WORDS * S_ROWS; idx += 1024)
        S[idx] = Mcol[idx];                // coalesced, 16-wave TLP
    __syncthreads();
    if (tid >= 64) return;                 // wave 0 continues alone (no barriers below)

    u64 lanebit = 1ull << lane;
    u64 riem0 = irem[lane];
    u64 riem1 = (lane < NWORDS - 64) ? irem[64 + lane] : ~0ull;

    int kc = 0, wend = 0;
    for (int w = 0; w < NWORDS && kc < POST_NMS_N; ++w) {
        int q0 = w << 6;
        u64 avail, myrow;

        if (w < S_WORDS) {
            u64 add = 0;
            for (int wp = 0; wp < w; ++wp) {
                u64 km = kmaskLDS[wp];
                if (km & lanebit) add |= S[w * S_ROWS + (wp << 6) + lane];
            }
            if (w) {
#pragma unroll
                for (int off = 32; off >= 1; off >>= 1) add |= __shfl_xor(add, off, 64);
            }
            u64 iw = readlane_u64(riem0, w);
            avail = ~(iw | add);
            u64 diag = S[w * S_ROWS + q0 + lane];
            bool ina = (avail >> lane) & 1ull;
            myrow = ina ? (diag & avail) : 0ull;
        } else {
            // exact on-the-fly fallback (only if >212 of first 512 suppressed);
            // performance-irrelevant never-path, reads global sboxes
            int j = q0 + lane; if (j >= PRE_NMS_N) j = PRE_NMS_N - 1;
            float4 bj = sboxes[j];
            bool sup = false;
            for (int wp = 0; wp < w; ++wp) {
                u64 km = kmaskLDS[wp];
                while (km) {
                    int b = __ffsll((unsigned long long)km) - 1; km &= km - 1;
                    sup = sup || iou_gt(sboxes[(wp << 6) + b], bj);
                }
            }
            u64 iw = (w < 64) ? readlane_u64(riem0, w) : readlane_u64(riem1, w - 64);
            avail = ~(iw | __ballot(sup));
            int irow = q0 + lane;
            bool rowok = (irow < PRE_NMS_N) && ((avail >> lane) & 1ull);
            float4 bi2 = sboxes[rowok ? irow : 0];
            u64 my = 0;
            for (int m2 = lane + 1; m2 < 64; ++m2) {
                int jj = q0 + m2;
                if (jj >= PRE_NMS_N) break;
                if (iou_gt(bi2, sboxes[jj])) my |= (1ull << m2);
            }
            myrow = rowok ? (my & avail) : 0ull;
        }

        u64 src = __ballot(myrow != 0ull);
        u64 tor = myrow;
#pragma unroll
        for (int off = 32; off >= 1; off >>= 1) tor |= __shfl_xor(tor, off, 64);
        u64 active = (src | tor) & avail;

        u64 rm = 0;
        while (active) {
            int b = __ffsll((unsigned long long)active) - 1;
            active &= active - 1;
            if (!((rm >> b) & 1ull)) rm |= readlane_u64(myrow, b);
        }
        u64 keptw = avail & ~rm;

        if (lane == 0) { kmaskLDS[w] = keptw; kbaseLDS[w] = (u32)kc; }
        kc += __popcll(keptw);
        wend = w + 1;
    }

    int nout = kc < POST_NMS_N ? kc : POST_NMS_N;
    for (int r2 = lane; r2 < POST_NMS_N; r2 += 64) {
        float4 v = make_float4(0.0f, 0.0f, 0.0f, 0.0f);
        if (r2 < nout) {
            int w = 0;
            while (w + 1 < wend && (int)kbaseLDS[w + 1] <= r2) ++w;
            int n = r2 - (int)kbaseLDS[w];
            int idx = (w << 6) + nth_set_bit(kmaskLDS[w], n);
            v = sboxes[idx];
        }
        ((float4*)out)[r2] = v;
    }
}

extern "C" void kernel_launch(void* const* d_in, const int* in_sizes, int n_in,
                              void* d_out, int out_size, void* d_ws, size_t ws_size,
                              hipStream_t stream) {
    const float4* anchors = (const float4*)d_in[0];
    const float*  cls     = (const float*)d_in[1];
    const float4* reg     = (const float4*)d_in[2];
    const int*    img_w   = (const int*)d_in[3];
    const int*    img_h   = (const int*)d_in[4];

    char* ws = (char*)d_ws;
    float4* bbox   = (float4*)(ws + OFF_BBOX);
    u64*    keys   = (u64*)   (ws + OFF_KEYS);
    float4* sboxes = (float4*)(ws + OFF_SBOX);
    u64*    irem   = (u64*)   (ws + OFF_IREM);
    u32*    bcnt   = (u32*)   (ws + OFF_BCNT);
    u64*    gkraw  = (u64*)   (ws + OFF_GKRAW);
    u64*    Mcol   = (u64*)   (ws + OFF_MCOL);

    k_decode<<<dim3(GRID_A), dim3(BLK_A), 0, stream>>>(
        anchors, cls, reg, img_w, img_h, bbox, keys, gkraw, bcnt);
    k_select<<<dim3(1), dim3(1024), 0, stream>>>(
        keys, gkraw, bcnt, bbox, sboxes, irem);
    k_eager<<<dim3(GRID_B), dim3(128), 0, stream>>>(sboxes, Mcol);
    k_reduce<<<dim3(1), dim3(1024), 0, stream>>>(
        sboxes, irem, Mcol, (float*)d_out);
}

// Round 22
// 39.623 us; speedup vs baseline: 2.3781x; 1.0820x over previous
//
#include <hip/hip_runtime.h>
#include <stdint.h>

typedef unsigned long long u64;
typedef unsigned int u32;

#define N_ANCH     36864
#define PRE_NMS_N  6000
#define POST_NMS_N 300
#define NBINS_F    8192     // fallback full bin count
#define NBINS_H    2048     // happy-path bins == prefilter width
#define PF_BIN     2048     // append keys with bin < 2048 (score >= 0.75): E=8018 >> 6000
#define SEG_CAP    112      // per-block segment cap (E=55.7, ~2x mean, P(ovf)~5e-8)
#define GKH_CAP    8192
#define NWORDS     94       // ceil(6000/64)
#define S_WORDS    8        // eager words (candidates 0..511)
#define S_ROWS     512
#define GRID_A     144      // 144 x 256 == N_ANCH
#define BLK_A      256
#define NSEG_TOT   (GRID_A * SEG_CAP)   // 16128 -- HARD BOUND for gkraw indexing
#define GRID_B     256      // rows {b, b+256} per block

// ---- workspace layout (bytes) ----
#define OFF_BBOX   0            // float4 bbox[36864]       589824
#define OFF_KEYS   589824       // u64 keys[36864]          294912 (fallback only)
#define OFF_SBOX   884736       // float4 sboxes[6000]       96000
#define OFF_IREM   980736       // u64 irem[94]                752
#define OFF_BCNT   981488       // u32 bcnt[144]               576
#define OFF_GKRAW  982064       // u64 gkraw[144*112]       129024
#define OFF_MCOL   1111088      // u64 Mcol[8*512]           32768 (word-major)
#define WS_FULL    (OFF_MCOL + (size_t)S_WORDS * S_ROWS * 8)

// Value-uniform monotone bin: higher score -> lower bin.
__device__ __forceinline__ u32 score_bin(float s) {
    float v = fminf(fmaxf(s, 0.0f), 1.0f);
    u32 q = (u32)(v * 8192.0f);
    if (q > 8191u) q = 8191u;
    return 8191u - q;
}

// key = bin(16) | sortable_score(32) | idx(16); ascending u64 ==
// (score desc, idx asc) exactly (bin monotone in score).
__device__ __forceinline__ u64 make_key(float s, u32 bin, u32 idx) {
    u32 u = __float_as_uint(s);
    u32 sortable = u ^ ((u >> 31) ? 0xFFFFFFFFu : 0x80000000u);
    u32 hi = ~sortable;
    return ((u64)bin << 48) | ((u64)hi << 16) | (u64)idx;
}

__device__ __forceinline__ u64 readlane_u64(u64 v, int l) {
    u32 lo = __builtin_amdgcn_readlane((u32)(v & 0xFFFFFFFFull), l);
    u32 hi = __builtin_amdgcn_readlane((u32)(v >> 32), l);
    return ((u64)hi << 32) | (u64)lo;
}

__device__ __forceinline__ int nth_set_bit(u64 m, int n) {
    int pos = 0;
    u32 c = __popc((u32)m);
    if ((u32)n >= c) { n -= c; pos = 32; m >>= 32; }
    u32 x = (u32)m;
    c = __popc(x & 0xFFFFu);
    if ((u32)n >= c) { n -= c; pos += 16; x >>= 16; }
    c = __popc(x & 0xFFu);
    if ((u32)n >= c) { n -= c; pos += 8; x >>= 8; }
    c = __popc(x & 0xFu);
    if ((u32)n >= c) { n -= c; pos += 4; x >>= 4; }
    c = __popc(x & 0x3u);
    if ((u32)n >= c) { n -= c; pos += 2; x >>= 2; }
    c = x & 1u;
    if ((u32)n >= c) { pos += 1; }
    return pos;
}

// EXACT reference IoU decision (identical expression tree to all prior rounds)
__device__ __forceinline__ bool iou_gt(float4 a, float4 b) {
    float aa = (a.z - a.x) * (a.w - a.y);
    float ab = (b.z - b.x) * (b.w - b.y);
    float xx1 = fmaxf(a.x, b.x), yy1 = fmaxf(a.y, b.y);
    float xx2 = fminf(a.z, b.z), yy2 = fminf(a.w, b.w);
    float inter = fmaxf(xx2 - xx1, 0.0f) * fmaxf(yy2 - yy1, 0.0f);
    float iou = inter / (aa + ab - inter + 1e-9f);
    return iou > 0.7f;
}

// ===== K_DECODE: 144 x 256; decode + segmented coalesced append (VERBATIM R20). =====
__global__ __launch_bounds__(BLK_A) void k_decode(const float4* __restrict__ anchors,
                                                  const float* __restrict__ cls,
                                                  const float4* __restrict__ reg,
                                                  const int* __restrict__ img_w,
                                                  const int* __restrict__ img_h,
                                                  float4* __restrict__ bbox,
                                                  u64* __restrict__ keys,
                                                  u64* __restrict__ gkraw,
                                                  u32* __restrict__ bcnt) {
    __shared__ u32 blkCnt;
    int tid = threadIdx.x, lane = tid & 63;
    int gi = blockIdx.x * BLK_A + tid;     // exact: 144*256 == N_ANCH

    if (tid == 0) blkCnt = 0u;
    __syncthreads();

    float4 a = anchors[gi];
    float4 r = reg[gi];
    float w  = a.z - a.x, h = a.w - a.y;
    float cx = a.x + 0.5f * w, cy = a.y + 0.5f * h;
    float pcx = r.x * w + cx, pcy = r.y * h + cy;
    float pw = expf(r.z) * w,  ph = expf(r.w) * h;
    float b0 = pcx - 0.5f * pw, b1 = pcy - 0.5f * ph;
    float b2 = pcx + 0.5f * pw, b3 = pcy + 0.5f * ph;

    float fh = (float)img_h[0], fw = (float)img_w[0];
    // reference: cols 0,2 clipped to [0, img_h]; cols 1,3 to [0, img_w]
    b0 = fminf(fmaxf(b0, 0.0f), fh);
    b2 = fminf(fmaxf(b2, 0.0f), fh);
    b1 = fminf(fmaxf(b1, 0.0f), fw);
    b3 = fminf(fmaxf(b3, 0.0f), fw);

    bool valid = (b2 - b0 >= 16.0f) && (b3 - b1 >= 16.0f);
    float score = valid ? cls[gi] : -1e9f;

    bbox[gi] = make_float4(b0, b1, b2, b3);
    u32 bin = score_bin(score);
    u64 key = make_key(score, bin, (u32)gi);
    keys[gi] = key;

    bool qf = bin < (u32)PF_BIN;
    u64 ball = __ballot(qf);
    u32 n = (u32)__popcll(ball);
    u32 wbase = 0;
    if (lane == 0 && n) wbase = atomicAdd(&blkCnt, n);
    wbase = (u32)__shfl((int)wbase, 0, 64);
    if (qf) {
        u32 pos = wbase + (u32)__popcll(ball & ((1ull << lane) - 1ull));
        if (pos < SEG_CAP) gkraw[(size_t)blockIdx.x * SEG_CAP + pos] = key;
    }

    __syncthreads();
    if (tid == 0) bcnt[blockIdx.x] = blkCnt;
}

// ===== K_SELECT: single block. bcnt staged to LDS (parallel loads); gkraw
//       register-cached with HARD BOUNDS (R21 bug: slots >= NSEG_TOT alias
//       Mcol, whose contents change across calls -> tripwire divergence). =====
__global__ __launch_bounds__(1024) void k_select(const u64* __restrict__ keys,
                                                 const u64* __restrict__ gkraw,
                                                 const u32* __restrict__ bcnt,
                                                 const float4* __restrict__ bbox,
                                                 float4* __restrict__ sboxes,
                                                 u64* __restrict__ irem) {
    __shared__ u32 histoffs[NBINS_H + 1];
    __shared__ u32 cntH[NBINS_H];
    __shared__ u32 wsum[16];
    __shared__ u64 gkB[GKH_CAP];
    __shared__ u32 psum[1024];
    __shared__ u32 histF[NBINS_F];
    __shared__ u32 cntF[NBINS_F];
    __shared__ u64 iremL[NWORDS];
    __shared__ u32 bcl[GRID_A];
    __shared__ u32 mB, mM, offs_top, totCnt, ovfFlag;

    int tid = threadIdx.x, lane = tid & 63, wave = tid >> 6;

    if (tid < NWORDS) iremL[tid] = ~0ull;
    if (tid == 0) ovfFlag = 0u;
    if (tid < GRID_A) bcl[tid] = bcnt[tid];   // 144 parallel loads, one round-trip

    // ---- register-cache gkraw slots (16/thread, static indexing, BOUNDED;
    //      independent loads issued before the barrier -> overlap bcl staging) ----
    u64 myk[16];
#pragma unroll
    for (int t = 0; t < 16; ++t) {
        int i = tid + t * 1024;
        myk[t] = gkraw[i < NSEG_TOT ? i : 0];  // clamp: never read past gkraw
    }
    __syncthreads();

    // ---- parallel count + overflow (2-barrier reduce) ----
    u32 myc = (tid < GRID_A) ? bcl[tid] : 0u;
    if (tid < GRID_A && myc > (u32)SEG_CAP) atomicOr(&ovfFlag, 1u);
    u32 cs = myc;
#pragma unroll
    for (int off = 1; off < 64; off <<= 1) cs += (u32)__shfl_xor((int)cs, off, 64);
    if (lane == 0) wsum[wave] = cs;
    __syncthreads();
    if (tid == 0) {
        u32 tot = 0;
#pragma unroll
        for (int k2 = 0; k2 < 16; ++k2) tot += wsum[k2];
        totCnt = tot;
    }
    __syncthreads();

    // validity mask: in-bounds slot AND within its block's count
    u32 vmask = 0;
#pragma unroll
    for (int t = 0; t < 16; ++t) {
        int i = tid + t * 1024;
        if (i < NSEG_TOT) {
            int b = i / SEG_CAP, o = i - b * SEG_CAP;
            if (o < (int)bcl[b]) vmask |= (1u << t);
        }
    }

    bool happy = (totCnt >= (u32)PRE_NMS_N) && (ovfFlag == 0u);

    if (happy) {
        // top-6000 subset proof: every non-appended key has bin >= PF_BIN >
        // any appended bin, and count >= 6000 appended keys exist.
        for (int b = tid; b < NBINS_H; b += 1024) { histoffs[b] = 0u; cntH[b] = 0u; }
        __syncthreads();
#pragma unroll
        for (int t = 0; t < 16; ++t)
            if (vmask & (1u << t))
                atomicAdd(&histoffs[(u32)(myk[t] >> 48)], 1u);
        __syncthreads();

        // 2-barrier block scan (shfl wave scan + 16-partial combine)
        u32 l0 = histoffs[2 * tid], l1 = histoffs[2 * tid + 1];
        u32 s = l0 + l1;
        u32 incv = s;
#pragma unroll
        for (int off = 1; off < 64; off <<= 1) {
            u32 v = (u32)__shfl_up((int)incv, off, 64);
            if (lane >= off) incv += v;
        }
        if (lane == 63) wsum[wave] = incv;
        __syncthreads();
        if (tid == 0) {
            u32 run = 0;
#pragma unroll
            for (int k2 = 0; k2 < 16; ++k2) { u32 t2 = wsum[k2]; wsum[k2] = run; run += t2; }
        }
        __syncthreads();
        u32 incl = wsum[wave] + incv;
        u32 excl = incl - s;
        histoffs[2 * tid] = excl;
        histoffs[2 * tid + 1] = excl + l0;
        if (tid == 1023) histoffs[NBINS_H] = incl;
        if (excl < (u32)PRE_NMS_N && incl >= (u32)PRE_NMS_N) {
            if (excl + l0 >= (u32)PRE_NMS_N) { mB = 2 * tid;     mM = excl + l0; }
            else                             { mB = 2 * tid + 1; mM = incl; }
        }
        __syncthreads();

        u32 B = mB;
#pragma unroll
        for (int t = 0; t < 16; ++t) {
            if (vmask & (1u << t)) {
                u64 k = myk[t];
                u32 bn = (u32)(k >> 48);
                if (bn <= B) {
                    u32 p = histoffs[bn] + atomicAdd(&cntH[bn], 1u);
                    if (p < (u32)GKH_CAP) gkB[p] = k;
                }
            }
        }
        __syncthreads();
        u32 Mtot = mM > (u32)GKH_CAP ? (u32)GKH_CAP : mM;
        for (int i = tid; i < (int)Mtot; i += 1024) {
            u64 k = gkB[i];
            u32 bn = (u32)(k >> 48);
            u32 st = histoffs[bn], en = histoffs[bn + 1];
            if (en > (u32)GKH_CAP) en = (u32)GKH_CAP;
            u32 rr = st;
            for (u32 t = st; t < en; ++t) rr += (gkB[t] < k) ? 1u : 0u;
            if (rr < (u32)PRE_NMS_N) {
                u32 idx = (u32)(k & 0xFFFFu);
                sboxes[rr] = bbox[idx];   // appended => bin<2048 => score>=0.75 => valid
            }
        }
        if (tid < 93) iremL[tid] = 0ull;
        if (tid == 93) iremL[93] = 0xFFFF000000000000ull;  // ranks 6000..6015 removed
    } else {
        // ---- exact fallback: full 8192-bin path over all keys (R8-proven) ----
        for (int b = tid; b < NBINS_F; b += 1024) { histF[b] = 0u; cntF[b] = 0u; }
        __syncthreads();
        for (int i = tid; i < N_ANCH; i += 1024)
            atomicAdd(&histF[(u32)(keys[i] >> 48)], 1u);
        __syncthreads();
        u32 loc[8]; u32 s = 0;
        int base8 = tid * 8;
#pragma unroll
        for (int t = 0; t < 8; ++t) { loc[t] = histF[base8 + t]; s += loc[t]; }
        psum[tid] = s;
        __syncthreads();
        for (int off = 1; off < 1024; off <<= 1) {
            u32 v = (tid >= off) ? psum[tid - off] : 0u;
            __syncthreads();
            psum[tid] += v;
            __syncthreads();
        }
        u32 incl = psum[tid], excl = incl - s;
        u32 run = excl;
#pragma unroll
        for (int t = 0; t < 8; ++t) { histF[base8 + t] = run; run += loc[t]; }
        if (tid == 1023) offs_top = incl;
        if (excl < (u32)PRE_NMS_N && incl >= (u32)PRE_NMS_N) {
            u32 c = excl;
#pragma unroll
            for (int t = 0; t < 8; ++t) {
                if (c + loc[t] >= (u32)PRE_NMS_N) { mB = (u32)(base8 + t); mM = c + loc[t]; break; }
                c += loc[t];
            }
        }
        __syncthreads();
        u32 B = mB;
        for (int i = tid; i < N_ANCH; i += 1024) {
            u64 k = keys[i];
            u32 bn = (u32)(k >> 48);
            if (bn <= B) {
                u32 p = histF[bn] + atomicAdd(&cntF[bn], 1u);
                if (p < (u32)GKH_CAP) gkB[p] = k;
            }
        }
        __syncthreads();
        u32 Mtot = mM > (u32)GKH_CAP ? (u32)GKH_CAP : mM;
        for (int i = tid; i < (int)Mtot; i += 1024) {
            u64 k = gkB[i];
            u32 bn = (u32)(k >> 48);
            u32 st = histF[bn];
            u32 en = (bn + 1 < (u32)NBINS_F) ? histF[bn + 1] : offs_top;
            if (en > (u32)GKH_CAP) en = (u32)GKH_CAP;
            u32 rr = st;
            for (u32 t = st; t < en; ++t) rr += (gkB[t] < k) ? 1u : 0u;
            if (rr < (u32)PRE_NMS_N) {
                u32 idx = (u32)(k & 0xFFFFu);
                float4 b = bbox[idx];
                sboxes[rr] = b;
                bool valid = (b.z - b.x >= 16.0f) && (b.w - b.y >= 16.0f);
                if (valid) atomicAnd(&iremL[rr >> 6], ~(1ull << (rr & 63)));
            }
        }
    }
    __syncthreads();
    if (tid < NWORDS) irem[tid] = iremL[tid];
}

// ===== K_EAGER: 128 threads/block -- wave t owns row b + t*256 (VERBATIM R20). =====
__global__ __launch_bounds__(128) void k_eager(const float4* __restrict__ sboxes,
                                               u64* __restrict__ Mcol) {
    int lane = threadIdx.x & 63, t = threadIdx.x >> 6;
    int i = blockIdx.x + (t << 8);         // < 512
    float4 bi = sboxes[i];
    for (int w = i >> 6; w < S_WORDS; ++w) {
        int j = (w << 6) + lane;           // < 512
        bool sup = (j > i) && iou_gt(bi, sboxes[j]);
        u64 m = __ballot(sup);             // wave-local
        if (lane == 0) Mcol[w * S_ROWS + i] = m;
    }
}

// ===== K_REDUCE: 1024-thread cooperative stage + wave-0 serial scan (VERBATIM R20). =====
__global__ __launch_bounds__(1024) void k_reduce(const float4* __restrict__ sboxes,
                                                 const u64* __restrict__ irem,
                                                 const u64* __restrict__ Mcol,
                                                 float* __restrict__ out) {
    __shared__ u64 S[S_WORDS * S_ROWS];    // 32768 B == Mcol layout
    __shared__ u64 kmaskLDS[NWORDS];
    __shared__ u32 kbaseLDS[NWORDS];
    int tid = threadIdx.x, lane = tid & 63;

    for (int idx = tid; idx < S_WORDS * S_ROWS; idx += 1024)
        S[idx] = Mcol[idx];                // coalesced, 16-wave TLP
    __syncthreads();
    if (tid >= 64) return;                 // wave 0 continues alone (no barriers below)

    u64 lanebit = 1ull << lane;
    u64 riem0 = irem[lane];
    u64 riem1 = (lane < NWORDS - 64) ? irem[64 + lane] : ~0ull;

    int kc = 0, wend = 0;
    for (int w = 0; w < NWORDS && kc < POST_NMS_N; ++w) {
        int q0 = w << 6;
        u64 avail, myrow;

        if (w < S_WORDS) {
            u64 add = 0;
            for (int wp = 0; wp < w; ++wp) {
                u64 km = kmaskLDS[wp];
                if (km & lanebit) add |= S[w * S_ROWS + (wp << 6) + lane];
            }
            if (w) {
#pragma unroll
                for (int off = 32; off >= 1; off >>= 1) add |= __shfl_xor(add, off, 64);
            }
            u64 iw = readlane_u64(riem0, w);
            avail = ~(iw | add);
            u64 diag = S[w * S_ROWS + q0 + lane];
            bool ina = (avail >> lane) & 1ull;
            myrow = ina ? (diag & avail) : 0ull;
        } else {
            // exact on-the-fly fallback (only if >212 of first 512 suppressed);
            // performance-irrelevant never-path, reads global sboxes
            int j = q0 + lane; if (j >= PRE_NMS_N) j = PRE_NMS_N - 1;
            float4 bj = sboxes[j];
            bool sup = false;
            for (int wp = 0; wp < w; ++wp) {
                u64 km = kmaskLDS[wp];
                while (km) {
                    int b = __ffsll((unsigned long long)km) - 1; km &= km - 1;
                    sup = sup || iou_gt(sboxes[(wp << 6) + b], bj);
                }
            }
            u64 iw = (w < 64) ? readlane_u64(riem0, w) : readlane_u64(riem1, w - 64);
            avail = ~(iw | __ballot(sup));
            int irow = q0 + lane;
            bool rowok = (irow < PRE_NMS_N) && ((avail >> lane) & 1ull);
            float4 bi2 = sboxes[rowok ? irow : 0];
            u64 my = 0;
            for (int m2 = lane + 1; m2 < 64; ++m2) {
                int jj = q0 + m2;
                if (jj >= PRE_NMS_N) break;
                if (iou_gt(bi2, sboxes[jj])) my |= (1ull << m2);
            }
            myrow = rowok ? (my & avail) : 0ull;
        }

        u64 src = __ballot(myrow != 0ull);
        u64 tor = myrow;
#pragma unroll
        for (int off = 32; off >= 1; off >>= 1) tor |= __shfl_xor(tor, off, 64);
        u64 active = (src | tor) & avail;

        u64 rm = 0;
        while (active) {
            int b = __ffsll((unsigned long long)active) - 1;
            active &= active - 1;
            if (!((rm >> b) & 1ull)) rm |= readlane_u64(myrow, b);
        }
        u64 keptw = avail & ~rm;

        if (lane == 0) { kmaskLDS[w] = keptw; kbaseLDS[w] = (u32)kc; }
        kc += __popcll(keptw);
        wend = w + 1;
    }

    int nout = kc < POST_NMS_N ? kc : POST_NMS_N;
    for (int r2 = lane; r2 < POST_NMS_N; r2 += 64) {
        float4 v = make_float4(0.0f, 0.0f, 0.0f, 0.0f);
        if (r2 < nout) {
            int w = 0;
            while (w + 1 < wend && (int)kbaseLDS[w + 1] <= r2) ++w;
            int n = r2 - (int)kbaseLDS[w];
            int idx = (w << 6) + nth_set_bit(kmaskLDS[w], n);
            v = sboxes[idx];
        }
        ((float4*)out)[r2] = v;
    }
}

extern "C" void kernel_launch(void* const* d_in, const int* in_sizes, int n_in,
                              void* d_out, int out_size, void* d_ws, size_t ws_size,
                              hipStream_t stream) {
    const float4* anchors = (const float4*)d_in[0];
    const float*  cls     = (const float*)d_in[1];
    const float4* reg     = (const float4*)d_in[2];
    const int*    img_w   = (const int*)d_in[3];
    const int*    img_h   = (const int*)d_in[4];

    char* ws = (char*)d_ws;
    float4* bbox   = (float4*)(ws + OFF_BBOX);
    u64*    keys   = (u64*)   (ws + OFF_KEYS);
    float4* sboxes = (float4*)(ws + OFF_SBOX);
    u64*    irem   = (u64*)   (ws + OFF_IREM);
    u32*    bcnt   = (u32*)   (ws + OFF_BCNT);
    u64*    gkraw  = (u64*)   (ws + OFF_GKRAW);
    u64*    Mcol   = (u64*)   (ws + OFF_MCOL);

    k_decode<<<dim3(GRID_A), dim3(BLK_A), 0, stream>>>(
        anchors, cls, reg, img_w, img_h, bbox, keys, gkraw, bcnt);
    k_select<<<dim3(1), dim3(1024), 0, stream>>>(
        keys, gkraw, bcnt, bbox, sboxes, irem);
    k_eager<<<dim3(GRID_B), dim3(128), 0, stream>>>(sboxes, Mcol);
    k_reduce<<<dim3(1), dim3(1024), 0, stream>>>(
        sboxes, irem, Mcol, (float*)d_out);
}